// Round 3
// baseline (491.602 us; speedup 1.0000x reference)
//
#include <hip/hip_runtime.h>
#include <hip/hip_bf16.h>

// Problem constants (B=16, F=8, NP=196, D=768, H=12)
#define BATCH 16
#define NFRAME 8
#define NPF 196          // tokens per frame
#define DIM 768
#define NHEAD 12
#define DHEAD 64
#define NTOK 1569        // 1 + 8*196
#define MROWS (BATCH * NTOK)   // 25104
#define D3 (3 * DIM)           // 2304
#define QKCOLS 1536      // Q+K columns kept in ws (bf16)
#define NKEY 197         // CLS + frame keys
#define NKP 224          // padded keys for PV (7*32)
#define NKQ 208          // padded keys for QK (13*16)
#define VST 232          // VT LDS row stride in shorts (464 B, 16B-aligned)
#define PSL 40           // P slice row stride in shorts (80 B, 16B-aligned)
#define SLICE_ELS (16 * PSL)   // one 16q x 32key slice (640 shorts = 1280 B)
#define NFBLK (BATCH * NHEAD * NFRAME)   // 1536 frame-attn blocks
#define CLSBLK (BATCH * NHEAD)           // 192 CLS blocks (dispatched FIRST)

typedef __attribute__((ext_vector_type(8))) short short8;
typedef __attribute__((ext_vector_type(4))) float floatx4;

#define MFMA16(A, B, C) __builtin_amdgcn_mfma_f32_16x16x32_bf16((A), (B), (C), 0, 0, 0)

__device__ __forceinline__ float bf2f(short s) {
    union { unsigned u; float f; } x;
    x.u = ((unsigned)(unsigned short)s) << 16;
    return x.f;
}
__device__ __forceinline__ short f2bf(float f) {
    union { float f; unsigned u; } x;
    x.f = f;
    unsigned r = x.u + 0x7fffu + ((x.u >> 16) & 1u);  // RNE
    return (short)(r >> 16);
}

// async global(bf16)->LDS, 16 bytes per lane
__device__ __forceinline__ void gld_lds16(const short* g, short* l) {
    __builtin_amdgcn_global_load_lds(
        (const __attribute__((address_space(1))) void*)g,
        (__attribute__((address_space(3))) void*)l, 16, 0, 0);
}

// ---------------------------------------------------------------------------
__global__ __launch_bounds__(256) void zero_out_k(float* __restrict__ out, int n) {
    int i = blockIdx.x * 256 + threadIdx.x;
    if (i < n) out[i] = 0.f;
}

// ---------------------------------------------------------------------------
// fp32 -> bf16 convert, 8 elements/thread
// ---------------------------------------------------------------------------
__global__ __launch_bounds__(256) void cvt_bf16_k(const float* __restrict__ in,
                                                  short* __restrict__ out, int n8) {
    int i = blockIdx.x * 256 + threadIdx.x;
    if (i < n8) {
        const float4* p = (const float4*)(in + (size_t)i * 8);
        float4 u0 = p[0], u1 = p[1];
        short8 t;
        t[0] = f2bf(u0.x); t[1] = f2bf(u0.y); t[2] = f2bf(u0.z); t[3] = f2bf(u0.w);
        t[4] = f2bf(u1.x); t[5] = f2bf(u1.y); t[6] = f2bf(u1.z); t[7] = f2bf(u1.w);
        *(short8*)(out + (size_t)i * 8) = t;
    }
}

// ---------------------------------------------------------------------------
// Weight transpose + fp32->bf16: in fp32 (R x C) -> out bf16 (C x R)
// ---------------------------------------------------------------------------
__global__ __launch_bounds__(256) void transpose_cvt_k(const float* __restrict__ in,
                                                       short* __restrict__ out,
                                                       int R, int C) {
    __shared__ float tile[32][33];
    int tx = threadIdx.x & 31, ty = threadIdx.x >> 5;
    int r0 = blockIdx.y * 32, c0 = blockIdx.x * 32;
    for (int i = 0; i < 4; ++i) {
        int r = ty + i * 8;
        tile[r][tx] = in[(size_t)(r0 + r) * C + c0 + tx];
    }
    __syncthreads();
    for (int i = 0; i < 4; ++i) {
        int c = ty + i * 8;
        out[(size_t)(c0 + c) * R + r0 + tx] = f2bf(tile[tx][c]);
    }
}

// ---------------------------------------------------------------------------
// 256x256-tile GEMM, BK=32, 8 waves (2Mx4N), 4-slot LDS ring (128 KiB),
// counted-vmcnt software pipeline (prefetch 3 K-tiles ahead), 1 raw barrier
// per K-tile, read-side XOR swizzle matched by pre-swizzled global source.
// C[M x Nc] = A[M x K] * BT[Nc x K]^T (+bias). Split store at col nsplit.
// grid = (Nc/256, ceil(M/256)), 512 threads.
// ---------------------------------------------------------------------------
template <bool OF32>
__global__ __launch_bounds__(512, 2) void gemm256(const short* __restrict__ A, int lda,
                                                  const short* __restrict__ BT,
                                                  const float* __restrict__ bias,
                                                  void* __restrict__ C0v, int ldc0,
                                                  void* __restrict__ C1v, int ldc1,
                                                  int nsplit, int M, int K) {
    // [slot][op A=0/B=1][256 rows x 32 k], 4 x 2 x 16KB = 128 KiB
    __shared__ __align__(16) short lds[4][2][256 * 32];

    const int tid = threadIdx.x;
    const int lane = tid & 63, wid = tid >> 6;
    const int l16 = lane & 15, quad = lane >> 4;
    const int wr = wid >> 2, wc = wid & 3;    // wave grid 2M x 4N
    const int n0 = blockIdx.x * 256, m0 = blockIdx.y * 256;
    const int T = K >> 5;                     // K-tiles of 32 (=24 here)

    // staging geometry: thread stages 2 x 16B chunks per unit (16KB unit)
    const int srow0 = tid >> 2;               // rows 0..127 (j=0), +128 (j=1)
    const int scd   = tid & 3;                // dest chunk

    floatx4 acc[8][4];
    #pragma unroll
    for (int mt = 0; mt < 8; ++mt)
        #pragma unroll
        for (int nt = 0; nt < 4; ++nt)
            acc[mt][nt] = (floatx4){0.f, 0.f, 0.f, 0.f};

    // ---- prologue: stage K-tiles 0,1,2 into slots 0,1,2 (order A(u),B(u))
    for (int u = 0; u < 3; ++u) {
        #pragma unroll
        for (int j = 0; j < 2; ++j) {
            int row = srow0 + j * 128;
            int cs = scd ^ ((row >> 1) & 3);
            int gr = m0 + row; if (gr >= M) gr = M - 1;
            gld_lds16(A + (size_t)gr * lda + u * 32 + cs * 8,
                      &lds[u][0][(j * 512 + tid) * 8]);
        }
        #pragma unroll
        for (int j = 0; j < 2; ++j) {
            int row = srow0 + j * 128;
            int cs = scd ^ ((row >> 1) & 3);
            gld_lds16(BT + (size_t)(n0 + row) * K + u * 32 + cs * 8,
                      &lds[u][1][(j * 512 + tid) * 8]);
        }
    }

    for (int t = 0; t < T; ++t) {
        const int slot = t & 3;
        const int sslot = (t + 3) & 3;
        const int kst = (t + 3) * 32;
        const bool do_stage = (t + 3) < T;

        // counted vmcnt: units in flight after tile t's = 4 (steady), 2, 0
        if (t + 2 < T)      asm volatile("s_waitcnt vmcnt(8)" ::: "memory");
        else if (t + 1 < T) asm volatile("s_waitcnt vmcnt(4)" ::: "memory");
        else                asm volatile("s_waitcnt vmcnt(0)" ::: "memory");
        __builtin_amdgcn_s_barrier();        // the only barrier per K-tile
        __builtin_amdgcn_sched_barrier(0);

        short8 bfr[4], afr[4];

        // ---- phase 0: stage A(t+3); compute rows wr*128 + [0,64)
        if (do_stage) {
            #pragma unroll
            for (int j = 0; j < 2; ++j) {
                int row = srow0 + j * 128;
                int cs = scd ^ ((row >> 1) & 3);
                int gr = m0 + row; if (gr >= M) gr = M - 1;
                gld_lds16(A + (size_t)gr * lda + kst + cs * 8,
                          &lds[sslot][0][(j * 512 + tid) * 8]);
            }
        }
        #pragma unroll
        for (int nt = 0; nt < 4; ++nt) {
            int row = wc * 64 + nt * 16 + l16;
            bfr[nt] = *(const short8*)&lds[slot][1][row * 32 + ((quad ^ ((row >> 1) & 3)) * 8)];
        }
        #pragma unroll
        for (int mt = 0; mt < 4; ++mt) {
            int row = wr * 128 + mt * 16 + l16;
            afr[mt] = *(const short8*)&lds[slot][0][row * 32 + ((quad ^ ((row >> 1) & 3)) * 8)];
        }
        __builtin_amdgcn_s_setprio(1);
        #pragma unroll
        for (int mt = 0; mt < 4; ++mt)
            #pragma unroll
            for (int nt = 0; nt < 4; ++nt)
                acc[mt][nt] = MFMA16(afr[mt], bfr[nt], acc[mt][nt]);
        __builtin_amdgcn_s_setprio(0);

        // ---- phase 1: stage B(t+3); compute rows wr*128 + [64,128)
        if (do_stage) {
            #pragma unroll
            for (int j = 0; j < 2; ++j) {
                int row = srow0 + j * 128;
                int cs = scd ^ ((row >> 1) & 3);
                gld_lds16(BT + (size_t)(n0 + row) * K + kst + cs * 8,
                          &lds[sslot][1][(j * 512 + tid) * 8]);
            }
        }
        #pragma unroll
        for (int mt = 0; mt < 4; ++mt) {
            int row = wr * 128 + 64 + mt * 16 + l16;
            afr[mt] = *(const short8*)&lds[slot][0][row * 32 + ((quad ^ ((row >> 1) & 3)) * 8)];
        }
        __builtin_amdgcn_s_setprio(1);
        #pragma unroll
        for (int mt = 0; mt < 4; ++mt)
            #pragma unroll
            for (int nt = 0; nt < 4; ++nt)
                acc[4 + mt][nt] = MFMA16(afr[mt], bfr[nt], acc[4 + mt][nt]);
        __builtin_amdgcn_s_setprio(0);
    }

    // ---- epilogue store
    #pragma unroll
    for (int mt = 0; mt < 8; ++mt)
        #pragma unroll
        for (int nt = 0; nt < 4; ++nt) {
            int col0 = n0 + wc * 64 + nt * 16;
            void* dst;
            int ldc, cbase;
            if (col0 < nsplit) { dst = C0v; ldc = ldc0; cbase = col0; }
            else               { dst = C1v; ldc = ldc1; cbase = col0 - nsplit; }
            float bv = bias ? bias[col0 + l16] : 0.f;
            #pragma unroll
            for (int r = 0; r < 4; ++r) {
                int row = m0 + wr * 128 + mt * 16 + quad * 4 + r;
                if (row < M) {
                    float v = acc[mt][nt][r] + bv;
                    if (OF32)
                        ((float*)dst)[(size_t)row * ldc + cbase + l16] = v;
                    else
                        ((short*)dst)[(size_t)row * ldc + cbase + l16] = f2bf(v);
                }
            }
        }
}

// ---------------------------------------------------------------------------
// Merged attention kernel (unchanged from round 2).
// ---------------------------------------------------------------------------
struct FrameLds {
    short K[NKQ * DHEAD];           // 26624 B, [key][d], 16B-slot XOR swizzle
    short VT[DHEAD * VST];          // 29696 B, [d][key] swizzled
    short P[4][2 * SLICE_ELS];      // 10240 B, per-wave P slices / O bounce
};
struct ClsLds {
    float qs[DHEAD];
    float sexp[NTOK];
    float red[8];
    float partial[4][DHEAD];
};
union AttnLds {
    FrameLds fa;
    ClsLds ca;
};

__global__ __launch_bounds__(256, 2) void attn_k(short* __restrict__ qk,
                                                 const short* __restrict__ vsrc) {
    __shared__ __align__(16) AttnLds u;

    if (blockIdx.x >= CLSBLK) {
        // ---------------- frame attention ----------------
        int blk = blockIdx.x - CLSBLK;
        int f = blk & 7;
        int h = (blk >> 3) % NHEAD;
        int b = blk / (NHEAD * NFRAME);
        int lane = threadIdx.x & 63, wid = threadIdx.x >> 6;
        int l16 = lane & 15, quad = lane >> 4;
        const size_t basetok = (size_t)b * NTOK;
        const int hc = h * DHEAD;
        short* Ks = u.fa.K;
        short* VT = u.fa.VT;
        short* Pw = u.fa.P[wid];

        // ---- V staging: coalesced short8 loads, swizzled transpose writes
        for (int c = threadIdx.x; c < NKP * DHEAD / 8; c += 256) {
            int j = c >> 3, dc = c & 7;
            short8 v = (short8){0, 0, 0, 0, 0, 0, 0, 0};
            if (j < NKEY) {
                int tok = (j == 0) ? 0 : (f * NPF + j);
                v = *(const short8*)(vsrc + (basetok + tok) * DIM + hc + dc * 8);
            }
            #pragma unroll
            for (int t = 0; t < 8; ++t) {
                int row = dc * 8 + t;
                int wb = row * (VST * 2) + j * 2;
                wb ^= (dc & 7) << 4;   // row>>3 == dc
                *(short*)((char*)VT + wb) = v[t];
            }
        }
        // ---- K staging: row-major [208][64], one short8 store per chunk
        for (int c = threadIdx.x; c < NKQ * DHEAD / 8; c += 256) {
            int j = c >> 3, dc = c & 7;
            short8 kv = (short8){0, 0, 0, 0, 0, 0, 0, 0};
            if (j < NKEY) {
                int tok = (j == 0) ? 0 : (f * NPF + j);
                kv = *(const short8*)(qk + (basetok + tok) * QKCOLS + DIM + hc + dc * 8);
            }
            int wb = (j * DHEAD + dc * 8) * 2;
            wb ^= (j & 7) << 4;
            *(short8*)((char*)Ks + wb) = kv;
        }
        __syncthreads();   // the only block-wide barrier

        const float scale = 0.125f;  // d^-0.5, d=64

        for (int qt = wid; qt < 13; qt += 4) {
            floatx4 S[13];
            for (int nt = 0; nt < 13; ++nt) S[nt] = (floatx4){0.f, 0.f, 0.f, 0.f};

            int qm = qt * 16 + l16;
            if (qm > 195) qm = 195;       // clamp pad rows (results discarded)
            int qtok = 1 + f * NPF + qm;
            const short* qrow = qk + (basetok + qtok) * QKCOLS + hc;
            short8 afrag[2];
            afrag[0] = *(const short8*)(qrow + quad * 8);
            afrag[1] = *(const short8*)(qrow + 32 + quad * 8);

            // QK^T from LDS K tile (2-way-free swizzled reads)
            int sw = (l16 & 7) << 4;     // key&7 == l16&7 (nt*16 is 0 mod 8)
            for (int nt = 0; nt < 13; ++nt) {
                int kb = (nt * 16 + l16) * 128 + quad * 16;
                short8 b0 = *(const short8*)((const char*)Ks + (kb ^ sw));
                short8 b1 = *(const short8*)((const char*)Ks + ((kb + 64) ^ sw));
                S[nt] = MFMA16(afrag[0], b0, S[nt]);
                S[nt] = MFMA16(afrag[1], b1, S[nt]);
            }

            for (int nt = 0; nt < 13; ++nt) {
                int key = nt * 16 + l16;
                float mask = (key < NKEY) ? 0.f : -1e30f;
                for (int r = 0; r < 4; ++r) S[nt][r] = S[nt][r] * scale + mask;
            }

            float inv_sum[4];
            for (int r = 0; r < 4; ++r) {
                float m = -1e30f;
                for (int nt = 0; nt < 13; ++nt) m = fmaxf(m, S[nt][r]);
                for (int off = 1; off < 16; off <<= 1) m = fmaxf(m, __shfl_xor(m, off, 64));
                float s = 0.f;
                for (int nt = 0; nt < 13; ++nt) {
                    float e = __expf(S[nt][r] - m);
                    S[nt][r] = e;
                    s += e;
                }
                for (int off = 1; off < 16; off <<= 1) s += __shfl_xor(s, off, 64);
                inv_sum[r] = 1.0f / s;
            }

            // ---- PV: stream P through a double-buffered 16x32 LDS slice.
            floatx4 O[4];
            for (int dt = 0; dt < 4; ++dt) O[dt] = (floatx4){0.f, 0.f, 0.f, 0.f};

            // prologue: write slice 0 (keys 0..31)
            #pragma unroll
            for (int nt2 = 0; nt2 < 2; ++nt2)
                #pragma unroll
                for (int r = 0; r < 4; ++r)
                    Pw[(quad * 4 + r) * PSL + nt2 * 16 + l16] = f2bf(S[nt2][r]);

            for (int ks = 0; ks < 7; ++ks) {
                const short* cur = Pw + (ks & 1) * SLICE_ELS;
                short8 af = *(const short8*)&cur[l16 * PSL + quad * 8];
                short8 bfr_[4];
                #pragma unroll
                for (int dt = 0; dt < 4; ++dt) {
                    int vrow = dt * 16 + l16;
                    int vb = vrow * (VST * 2) + ks * 64 + quad * 16;
                    vb ^= ((vrow >> 3) & 7) << 4;
                    bfr_[dt] = *(const short8*)((const char*)VT + vb);
                }
                if (ks < 6) {   // write next slice; MFMA below hides the latency
                    short* nxt = Pw + ((ks + 1) & 1) * SLICE_ELS;
                    #pragma unroll
                    for (int nt2 = 0; nt2 < 2; ++nt2)
                        #pragma unroll
                        for (int r = 0; r < 4; ++r) {
                            int idx = 2 * (ks + 1) + nt2;
                            nxt[(quad * 4 + r) * PSL + nt2 * 16 + l16] =
                                (idx < 13) ? f2bf(S[idx][r]) : (short)0;
                        }
                }
                #pragma unroll
                for (int dt = 0; dt < 4; ++dt)
                    O[dt] = MFMA16(af, bfr_[dt], O[dt]);
            }

            // ---- O: bounce through LDS -> coalesced full-line stores
            short* Ob = Pw;   // reuse per-wave P area as [16][80]
            #pragma unroll
            for (int dt = 0; dt < 4; ++dt)
                #pragma unroll
                for (int r = 0; r < 4; ++r)
                    Ob[(quad * 4 + r) * 80 + dt * 16 + l16] = f2bf(O[dt][r] * inv_sum[r]);
            int orow = lane >> 2, oseg = lane & 3;
            short8 o0 = *(const short8*)&Ob[orow * 80 + oseg * 16];
            short8 o1 = *(const short8*)&Ob[orow * 80 + oseg * 16 + 8];
            int m = qt * 16 + orow;
            if (m < NPF) {
                short* dst = qk + (basetok + (1 + f * NPF + m)) * QKCOLS + hc + oseg * 16;
                *(short8*)dst = o0;
                *(short8*)(dst + 8) = o1;
            }
        }
    } else {
        // ---------------- CLS attention ----------------
        int cblk = blockIdx.x;
        int h = cblk % NHEAD, b = cblk / NHEAD;
        const size_t basetok = (size_t)b * NTOK;
        const int hc = h * DHEAD;
        int tid = threadIdx.x;
        ClsLds& ca = u.ca;

        if (tid < DHEAD) ca.qs[tid] = bf2f(qk[basetok * QKCOLS + hc + tid]) * 0.125f;
        __syncthreads();

        float lmax = -1e30f;
        for (int j = tid; j < NTOK; j += 256) {
            const short* krow = qk + (basetok + j) * QKCOLS + DIM + hc;
            float s = 0.f;
            #pragma unroll
            for (int c = 0; c < 8; ++c) {
                short8 kv = *(const short8*)(krow + c * 8);
                const float4* qp = (const float4*)&ca.qs[c * 8];
                float4 q0 = qp[0], q1 = qp[1];
                s += q0.x * bf2f(kv[0]); s += q0.y * bf2f(kv[1]);
                s += q0.z * bf2f(kv[2]); s += q0.w * bf2f(kv[3]);
                s += q1.x * bf2f(kv[4]); s += q1.y * bf2f(kv[5]);
                s += q1.z * bf2f(kv[6]); s += q1.w * bf2f(kv[7]);
            }
            ca.sexp[j] = s;
            lmax = fmaxf(lmax, s);
        }
        for (int off = 1; off < 64; off <<= 1) lmax = fmaxf(lmax, __shfl_xor(lmax, off, 64));
        if ((tid & 63) == 0) ca.red[tid >> 6] = lmax;
        __syncthreads();
        float mx = fmaxf(fmaxf(ca.red[0], ca.red[1]), fmaxf(ca.red[2], ca.red[3]));

        float lsum = 0.f;
        for (int j = tid; j < NTOK; j += 256) {
            float e = __expf(ca.sexp[j] - mx);
            ca.sexp[j] = e;
            lsum += e;
        }
        for (int off = 1; off < 64; off <<= 1) lsum += __shfl_xor(lsum, off, 64);
        if ((tid & 63) == 0) ca.red[4 + (tid >> 6)] = lsum;
        __syncthreads();
        float sum = ca.red[4] + ca.red[5] + ca.red[6] + ca.red[7];

        int dd = tid & 63, strip = tid >> 6;
        float acc = 0.f;
        for (int j = strip; j < NTOK; j += 4)
            acc += ca.sexp[j] * bf2f(vsrc[(basetok + j) * DIM + hc + dd]);
        ca.partial[strip][dd] = acc;
        __syncthreads();

        if (tid < DHEAD) {
            float o = (ca.partial[0][tid] + ca.partial[1][tid] +
                       ca.partial[2][tid] + ca.partial[3][tid]) / sum;
            qk[basetok * QKCOLS + hc + tid] = f2bf(o);
        }
    }
}

// ---------------------------------------------------------------------------
extern "C" void kernel_launch(void* const* d_in, const int* in_sizes, int n_in,
                              void* d_out, int out_size, void* d_ws, size_t ws_size,
                              hipStream_t stream) {
    const float* x      = (const float*)d_in[0];   // (B, N, D) fp32
    const float* w_qkv  = (const float*)d_in[1];   // (D, 3D) fp32
    const float* w_proj = (const float*)d_in[2];   // (D, D) fp32
    const float* b_proj = (const float*)d_in[3];   // (D,) fp32
    float* out = (float*)d_out;                    // fp32 output (77.1 MB)

    // d_out doubles as scratch pre-proj: [xbf 38.56 MB | vbuf 38.56 MB]
    short* xbf  = (short*)d_out;
    short* vbuf = (short*)d_out + (size_t)MROWS * DIM;

    // ws: qk bf16 (MROWS x 1536) | wqkvT (2304x768) | wprojT (768x768) = ~82 MB
    const size_t QK_EL     = (size_t)MROWS * QKCOLS;
    const size_t WQKVT_EL  = (size_t)D3 * DIM;
    const size_t WPROJT_EL = (size_t)DIM * DIM;
    const size_t WS_NEEDED = (QK_EL + WQKVT_EL + WPROJT_EL) * sizeof(short);

    if (ws_size < WS_NEEDED) {
        zero_out_k<<<(out_size + 255) / 256, 256, 0, stream>>>(out, out_size);
        return;
    }

    short* qk     = (short*)d_ws;
    short* wqkvT  = qk + QK_EL;
    short* wprojT = wqkvT + WQKVT_EL;

    cvt_bf16_k<<<(MROWS * DIM / 8 + 255) / 256, 256, 0, stream>>>(x, xbf, MROWS * DIM / 8);
    transpose_cvt_k<<<dim3(D3 / 32, DIM / 32), 256, 0, stream>>>(w_qkv, wqkvT, DIM, D3);
    transpose_cvt_k<<<dim3(DIM / 32, DIM / 32), 256, 0, stream>>>(w_proj, wprojT, DIM, DIM);

    // qkv = xbf @ w_qkv ; cols 0..1535 (Q,K) -> qk, cols 1536.. (V) -> vbuf
    gemm256<false><<<dim3(D3 / 256, (MROWS + 255) / 256), 512, 0, stream>>>(
        xbf, DIM, wqkvT, nullptr, qk, QKCOLS, vbuf, DIM, QKCOLS, MROWS, DIM);

    attn_k<<<NFBLK + CLSBLK, 256, 0, stream>>>(qk, vbuf);

    // out = attnout @ w_proj + b_proj (attnout = qk's Q region, lda=1536; fp32 out)
    gemm256<true><<<dim3(DIM / 256, (MROWS + 255) / 256), 512, 0, stream>>>(
        qk, QKCOLS, wprojT, b_proj, out, DIM, nullptr, 0, 2 * DIM /*no split*/,
        MROWS, DIM);
}

// Round 4
// 474.424 us; speedup vs baseline: 1.0362x; 1.0362x over previous
//
#include <hip/hip_runtime.h>
#include <hip/hip_bf16.h>

// Problem constants (B=16, F=8, NP=196, D=768, H=12)
#define BATCH 16
#define NFRAME 8
#define NPF 196          // tokens per frame
#define DIM 768
#define NHEAD 12
#define DHEAD 64
#define NTOK 1569        // 1 + 8*196
#define MROWS (BATCH * NTOK)   // 25104
#define D3 (3 * DIM)           // 2304
#define QKCOLS 1536      // Q+K columns kept in ws (bf16)
#define NKEY 197         // CLS + frame keys
#define NKP 224          // padded keys for PV (7*32)
#define NKQ 208          // padded keys for QK (13*16)
#define VST 232          // VT LDS row stride in shorts (464 B, 16B-aligned)
#define PSL 40           // P slice row stride in shorts (80 B, 16B-aligned)
#define SLICE_ELS (16 * PSL)   // one 16q x 32key slice (640 shorts = 1280 B)
#define NFBLK (BATCH * NHEAD * NFRAME)   // 1536 frame-attn blocks
#define CLSBLK (BATCH * NHEAD)           // 192 CLS blocks (dispatched FIRST)

typedef __attribute__((ext_vector_type(8))) short short8;
typedef __attribute__((ext_vector_type(4))) float floatx4;

#define MFMA16(A, B, C) __builtin_amdgcn_mfma_f32_16x16x32_bf16((A), (B), (C), 0, 0, 0)

__device__ __forceinline__ float bf2f(short s) {
    union { unsigned u; float f; } x;
    x.u = ((unsigned)(unsigned short)s) << 16;
    return x.f;
}
__device__ __forceinline__ short f2bf(float f) {
    union { float f; unsigned u; } x;
    x.f = f;
    unsigned r = x.u + 0x7fffu + ((x.u >> 16) & 1u);  // RNE
    return (short)(r >> 16);
}

// async global(bf16)->LDS, 16 bytes per lane
__device__ __forceinline__ void gld_lds16(const short* g, short* l) {
    __builtin_amdgcn_global_load_lds(
        (const __attribute__((address_space(1))) void*)g,
        (__attribute__((address_space(3))) void*)l, 16, 0, 0);
}

// bijective XCD swizzle (m204): consecutive work-ids land on one XCD's blocks
__device__ __forceinline__ int xcd_swizzle(int d, int nwg) {
    int q = nwg >> 3, r = nwg & 7;
    int xcd = d & 7, j = d >> 3;
    return (xcd < r ? xcd * (q + 1) : r * (q + 1) + (xcd - r) * q) + j;
}

// ---------------------------------------------------------------------------
__global__ __launch_bounds__(256) void zero_out_k(float* __restrict__ out, int n) {
    int i = blockIdx.x * 256 + threadIdx.x;
    if (i < n) out[i] = 0.f;
}

// ---------------------------------------------------------------------------
// fp32 -> bf16 convert, 8 elements/thread
// ---------------------------------------------------------------------------
__global__ __launch_bounds__(256) void cvt_bf16_k(const float* __restrict__ in,
                                                  short* __restrict__ out, int n8) {
    int i = blockIdx.x * 256 + threadIdx.x;
    if (i < n8) {
        const float4* p = (const float4*)(in + (size_t)i * 8);
        float4 u0 = p[0], u1 = p[1];
        short8 t;
        t[0] = f2bf(u0.x); t[1] = f2bf(u0.y); t[2] = f2bf(u0.z); t[3] = f2bf(u0.w);
        t[4] = f2bf(u1.x); t[5] = f2bf(u1.y); t[6] = f2bf(u1.z); t[7] = f2bf(u1.w);
        *(short8*)(out + (size_t)i * 8) = t;
    }
}

// ---------------------------------------------------------------------------
// Weight transpose + fp32->bf16: in fp32 (R x C) -> out bf16 (C x R)
// ---------------------------------------------------------------------------
__global__ __launch_bounds__(256) void transpose_cvt_k(const float* __restrict__ in,
                                                       short* __restrict__ out,
                                                       int R, int C) {
    __shared__ float tile[32][33];
    int tx = threadIdx.x & 31, ty = threadIdx.x >> 5;
    int r0 = blockIdx.y * 32, c0 = blockIdx.x * 32;
    for (int i = 0; i < 4; ++i) {
        int r = ty + i * 8;
        tile[r][tx] = in[(size_t)(r0 + r) * C + c0 + tx];
    }
    __syncthreads();
    for (int i = 0; i < 4; ++i) {
        int c = ty + i * 8;
        out[(size_t)(c0 + c) * R + r0 + tx] = f2bf(tile[tx][c]);
    }
}

// ---------------------------------------------------------------------------
// LDS-tiled GEMM (m97 structure, 128x128): used for the proj GEMM where the
// 256-tile grid would have a heavy dispatch tail (only 3 column blocks).
// 1-D grid + bijective XCD swizzle.
// ---------------------------------------------------------------------------
template <bool OF32>
__global__ __launch_bounds__(256) void gemm_lds(const short* __restrict__ A, int lda,
                                                const short* __restrict__ BT,
                                                const float* __restrict__ bias,
                                                void* __restrict__ C0v, int ldc0,
                                                void* __restrict__ C1v, int ldc1,
                                                int nsplit, int M, int K,
                                                int gx, int nwg) {
    __shared__ __align__(16) short As[128 * 32];
    __shared__ __align__(16) short Bs[128 * 32];

    int tid = threadIdx.x;
    int lane = tid & 63, wid = tid >> 6;
    int l16 = lane & 15, quad = lane >> 4;
    int wg = xcd_swizzle(blockIdx.x, nwg);
    int n0 = (wg % gx) * 128, m0 = (wg / gx) * 128;
    int wm = (wid & 1) * 64, wn = (wid >> 1) * 64;

    int id0 = tid, id1 = tid + 256;
    int ar0 = id0 >> 2, ak0 = (id0 & 3) * 8;
    int ar1 = id1 >> 2, ak1 = (id1 & 3) * 8;
    int ga0 = m0 + ar0; if (ga0 >= M) ga0 = M - 1;
    int ga1 = m0 + ar1; if (ga1 >= M) ga1 = M - 1;
    const short* Ap0 = A + (size_t)ga0 * lda + ak0;
    const short* Ap1 = A + (size_t)ga1 * lda + ak1;
    const short* Bp0 = BT + (size_t)(n0 + ar0) * K + ak0;
    const short* Bp1 = BT + (size_t)(n0 + ar1) * K + ak1;

    floatx4 acc[4][4];
    for (int mt = 0; mt < 4; ++mt)
        for (int nt = 0; nt < 4; ++nt)
            acc[mt][nt] = (floatx4){0.f, 0.f, 0.f, 0.f};

    for (int k0 = 0; k0 < K; k0 += 32) {
        if (k0) __syncthreads();
        gld_lds16(Ap0 + k0, &As[id0 * 8]);
        gld_lds16(Ap1 + k0, &As[id1 * 8]);
        gld_lds16(Bp0 + k0, &Bs[id0 * 8]);
        gld_lds16(Bp1 + k0, &Bs[id1 * 8]);
        __syncthreads();

        short8 a[4], b[4];
        for (int mt = 0; mt < 4; ++mt)
            a[mt] = *(const short8*)&As[(wm + mt * 16 + l16) * 32 + quad * 8];
        for (int nt = 0; nt < 4; ++nt)
            b[nt] = *(const short8*)&Bs[(wn + nt * 16 + l16) * 32 + quad * 8];
        for (int mt = 0; mt < 4; ++mt)
            for (int nt = 0; nt < 4; ++nt)
                acc[mt][nt] = MFMA16(a[mt], b[nt], acc[mt][nt]);
    }

    for (int mt = 0; mt < 4; ++mt)
        for (int nt = 0; nt < 4; ++nt) {
            int col0 = n0 + wn + nt * 16;
            void* dst;
            int ldc, cbase;
            if (col0 < nsplit) { dst = C0v; ldc = ldc0; cbase = col0; }
            else               { dst = C1v; ldc = ldc1; cbase = col0 - nsplit; }
            float bv = bias ? bias[col0 + l16] : 0.f;
            for (int r = 0; r < 4; ++r) {
                int row = m0 + wm + mt * 16 + quad * 4 + r;
                if (row < M) {
                    float v = acc[mt][nt][r] + bv;
                    if (OF32)
                        ((float*)dst)[(size_t)row * ldc + cbase + l16] = v;
                    else
                        ((short*)dst)[(size_t)row * ldc + cbase + l16] = f2bf(v);
                }
            }
        }
}

// ---------------------------------------------------------------------------
// 256x256-tile GEMM, BK=32, 8 waves (2Mx4N), 4-slot LDS ring (128 KiB),
// counted-vmcnt pipeline (3 K-tiles ahead) with the m201 FINE-PHASE schedule:
// each K-tile = 2 phases of {ds_read frags; 2 global_load_lds; barrier;
// lgkmcnt(0); setprio(1); 16 MFMA; setprio(0); barrier}; boundary vmcnt(8)
// once per K-tile. Read-side XOR swizzle matched by pre-swizzled source.
// 1-D grid (nwg blocks) + bijective XCD swizzle.
// ---------------------------------------------------------------------------
#define G256_STAGE(OP, PTR, LD, CLAMP)                                          \
    {                                                                           \
        _Pragma("unroll")                                                       \
        for (int j = 0; j < 2; ++j) {                                           \
            int row = (w << 5) + (j << 4) + (lane >> 2);                        \
            int gr = (CLAMP) + row;                                             \
            if (gr >= (CLAMP##_max)) gr = (CLAMP##_max) - 1;                    \
            gld_lds16((PTR) + (size_t)gr * (LD) + kst + lcs,                    \
                      &lds[ss][OP][((w << 7) + (j << 6) + lane) * 8]);          \
        }                                                                       \
    }

template <bool OF32>
__global__ __launch_bounds__(512, 2) void gemm256(const short* __restrict__ A, int lda,
                                                  const short* __restrict__ BT,
                                                  const float* __restrict__ bias,
                                                  void* __restrict__ C0v, int ldc0,
                                                  void* __restrict__ C1v, int ldc1,
                                                  int nsplit, int M, int K,
                                                  int gx, int nwg) {
    // [slot][op A=0/B=1][256 rows x 32 k], 4 x 2 x 16KB = 128 KiB
    __shared__ __align__(16) short lds[4][2][256 * 32];

    const int tid = threadIdx.x;
    const int lane = tid & 63, w = tid >> 6;
    const int l16 = lane & 15, quad = lane >> 4;
    const int wr = w >> 2, wc = w & 3;        // wave grid 2M x 4N
    const int wg = xcd_swizzle(blockIdx.x, nwg);
    const int n0 = (wg % gx) * 256, m0 = (wg / gx) * 256;
    const int T = K >> 5;                     // K-tiles of 32

    // staging: source chunk pre-swizzle (element offset)
    const int lcs = ((lane & 3) ^ ((lane >> 3) & 3)) * 8;

    // fragment read offsets (shorts), loop-invariant
    int offA[8], offB[4];
    #pragma unroll
    for (int mt = 0; mt < 8; ++mt) {
        int row = wr * 128 + mt * 16 + l16;
        offA[mt] = row * 32 + (quad ^ ((row >> 1) & 3)) * 8;
    }
    #pragma unroll
    for (int nt = 0; nt < 4; ++nt) {
        int row = wc * 64 + nt * 16 + l16;
        offB[nt] = row * 32 + (quad ^ ((row >> 1) & 3)) * 8;
    }

    floatx4 acc[8][4];
    #pragma unroll
    for (int mt = 0; mt < 8; ++mt)
        #pragma unroll
        for (int nt = 0; nt < 4; ++nt)
            acc[mt][nt] = (floatx4){0.f, 0.f, 0.f, 0.f};

    const int M_max = M, N_max = 0x7fffffff;  // B rows always in-bounds here

    // ---- prologue: stage K-tiles 0,1,2 into slots 0,1,2
    for (int u = 0; u < 3; ++u) {
        const int ss = u, kst = u * 32;
        {
            #pragma unroll
            for (int j = 0; j < 2; ++j) {
                int row = (w << 5) + (j << 4) + (lane >> 2);
                int gr = m0 + row; if (gr >= M) gr = M - 1;
                gld_lds16(A + (size_t)gr * lda + kst + lcs,
                          &lds[ss][0][((w << 7) + (j << 6) + lane) * 8]);
            }
            #pragma unroll
            for (int j = 0; j < 2; ++j) {
                int row = (w << 5) + (j << 4) + (lane >> 2);
                gld_lds16(BT + (size_t)(n0 + row) * K + kst + lcs,
                          &lds[ss][1][((w << 7) + (j << 6) + lane) * 8]);
            }
        }
    }
    asm volatile("s_waitcnt vmcnt(8)" ::: "memory");   // tile 0 landed
    __builtin_amdgcn_s_barrier();

    for (int t = 0; t < T; ++t) {
        const int slot = t & 3;
        const int ss = (t + 3) & 3;
        const int kst = (t + 3) << 5;
        const bool do_stage = (t + 3) < T;
        const short* baseA = &lds[slot][0][0];
        const short* baseB = &lds[slot][1][0];

        short8 bfr[4], afr[4];

        // ================= phase 0: B-frags + A-frags mt0-3; stage A(t+3)
        #pragma unroll
        for (int nt = 0; nt < 4; ++nt) bfr[nt] = *(const short8*)(baseB + offB[nt]);
        #pragma unroll
        for (int mt = 0; mt < 4; ++mt) afr[mt] = *(const short8*)(baseA + offA[mt]);
        if (do_stage) {
            #pragma unroll
            for (int j = 0; j < 2; ++j) {
                int row = (w << 5) + (j << 4) + (lane >> 2);
                int gr = m0 + row; if (gr >= M) gr = M - 1;
                gld_lds16(A + (size_t)gr * lda + kst + lcs,
                          &lds[ss][0][((w << 7) + (j << 6) + lane) * 8]);
            }
        }
        __builtin_amdgcn_s_barrier();
        asm volatile("s_waitcnt lgkmcnt(0)" ::: "memory");
        __builtin_amdgcn_sched_barrier(0);
        __builtin_amdgcn_s_setprio(1);
        #pragma unroll
        for (int mt = 0; mt < 4; ++mt)
            #pragma unroll
            for (int nt = 0; nt < 4; ++nt)
                acc[mt][nt] = MFMA16(afr[mt], bfr[nt], acc[mt][nt]);
        __builtin_amdgcn_s_setprio(0);
        __builtin_amdgcn_s_barrier();

        // ================= phase 1: A-frags mt4-7; stage B(t+3)
        #pragma unroll
        for (int mt = 0; mt < 4; ++mt) afr[mt] = *(const short8*)(baseA + offA[4 + mt]);
        if (do_stage) {
            #pragma unroll
            for (int j = 0; j < 2; ++j) {
                int row = (w << 5) + (j << 4) + (lane >> 2);
                gld_lds16(BT + (size_t)(n0 + row) * K + kst + lcs,
                          &lds[ss][1][((w << 7) + (j << 6) + lane) * 8]);
            }
        }
        __builtin_amdgcn_s_barrier();
        asm volatile("s_waitcnt lgkmcnt(0)" ::: "memory");
        __builtin_amdgcn_sched_barrier(0);
        __builtin_amdgcn_s_setprio(1);
        #pragma unroll
        for (int mt = 0; mt < 4; ++mt)
            #pragma unroll
            for (int nt = 0; nt < 4; ++nt)
                acc[4 + mt][nt] = MFMA16(afr[mt], bfr[nt], acc[4 + mt][nt]);
        __builtin_amdgcn_s_setprio(0);
        // boundary: confirm tile t+1 (once per K-tile, counted, never 0 in steady)
        if (t + 1 < T) {
            if (t + 3 < T)      asm volatile("s_waitcnt vmcnt(8)" ::: "memory");
            else if (t + 2 < T) asm volatile("s_waitcnt vmcnt(4)" ::: "memory");
            else                asm volatile("s_waitcnt vmcnt(0)" ::: "memory");
        }
        __builtin_amdgcn_s_barrier();
    }
    (void)N_max;

    // ---- epilogue store
    #pragma unroll
    for (int mt = 0; mt < 8; ++mt)
        #pragma unroll
        for (int nt = 0; nt < 4; ++nt) {
            int col0 = n0 + wc * 64 + nt * 16;
            void* dst;
            int ldc, cbase;
            if (col0 < nsplit) { dst = C0v; ldc = ldc0; cbase = col0; }
            else               { dst = C1v; ldc = ldc1; cbase = col0 - nsplit; }
            float bv = bias ? bias[col0 + l16] : 0.f;
            #pragma unroll
            for (int r = 0; r < 4; ++r) {
                int row = m0 + wr * 128 + mt * 16 + quad * 4 + r;
                if (row < M) {
                    float v = acc[mt][nt][r] + bv;
                    if (OF32)
                        ((float*)dst)[(size_t)row * ldc + cbase + l16] = v;
                    else
                        ((short*)dst)[(size_t)row * ldc + cbase + l16] = f2bf(v);
                }
            }
        }
}

// ---------------------------------------------------------------------------
// Merged attention kernel (unchanged from round 2).
// ---------------------------------------------------------------------------
struct FrameLds {
    short K[NKQ * DHEAD];           // 26624 B, [key][d], 16B-slot XOR swizzle
    short VT[DHEAD * VST];          // 29696 B, [d][key] swizzled
    short P[4][2 * SLICE_ELS];      // 10240 B, per-wave P slices / O bounce
};
struct ClsLds {
    float qs[DHEAD];
    float sexp[NTOK];
    float red[8];
    float partial[4][DHEAD];
};
union AttnLds {
    FrameLds fa;
    ClsLds ca;
};

__global__ __launch_bounds__(256, 2) void attn_k(short* __restrict__ qk,
                                                 const short* __restrict__ vsrc) {
    __shared__ __align__(16) AttnLds u;

    if (blockIdx.x >= CLSBLK) {
        // ---------------- frame attention ----------------
        int blk = blockIdx.x - CLSBLK;
        int f = blk & 7;
        int h = (blk >> 3) % NHEAD;
        int b = blk / (NHEAD * NFRAME);
        int lane = threadIdx.x & 63, wid = threadIdx.x >> 6;
        int l16 = lane & 15, quad = lane >> 4;
        const size_t basetok = (size_t)b * NTOK;
        const int hc = h * DHEAD;
        short* Ks = u.fa.K;
        short* VT = u.fa.VT;
        short* Pw = u.fa.P[wid];

        // ---- V staging: coalesced short8 loads, swizzled transpose writes
        for (int c = threadIdx.x; c < NKP * DHEAD / 8; c += 256) {
            int j = c >> 3, dc = c & 7;
            short8 v = (short8){0, 0, 0, 0, 0, 0, 0, 0};
            if (j < NKEY) {
                int tok = (j == 0) ? 0 : (f * NPF + j);
                v = *(const short8*)(vsrc + (basetok + tok) * DIM + hc + dc * 8);
            }
            #pragma unroll
            for (int t = 0; t < 8; ++t) {
                int row = dc * 8 + t;
                int wb = row * (VST * 2) + j * 2;
                wb ^= (dc & 7) << 4;   // row>>3 == dc
                *(short*)((char*)VT + wb) = v[t];
            }
        }
        // ---- K staging: row-major [208][64], one short8 store per chunk
        for (int c = threadIdx.x; c < NKQ * DHEAD / 8; c += 256) {
            int j = c >> 3, dc = c & 7;
            short8 kv = (short8){0, 0, 0, 0, 0, 0, 0, 0};
            if (j < NKEY) {
                int tok = (j == 0) ? 0 : (f * NPF + j);
                kv = *(const short8*)(qk + (basetok + tok) * QKCOLS + DIM + hc + dc * 8);
            }
            int wb = (j * DHEAD + dc * 8) * 2;
            wb ^= (j & 7) << 4;
            *(short8*)((char*)Ks + wb) = kv;
        }
        __syncthreads();   // the only block-wide barrier

        const float scale = 0.125f;  // d^-0.5, d=64

        for (int qt = wid; qt < 13; qt += 4) {
            floatx4 S[13];
            for (int nt = 0; nt < 13; ++nt) S[nt] = (floatx4){0.f, 0.f, 0.f, 0.f};

            int qm = qt * 16 + l16;
            if (qm > 195) qm = 195;       // clamp pad rows (results discarded)
            int qtok = 1 + f * NPF + qm;
            const short* qrow = qk + (basetok + qtok) * QKCOLS + hc;
            short8 afrag[2];
            afrag[0] = *(const short8*)(qrow + quad * 8);
            afrag[1] = *(const short8*)(qrow + 32 + quad * 8);

            // QK^T from LDS K tile (2-way-free swizzled reads)
            int sw = (l16 & 7) << 4;     // key&7 == l16&7 (nt*16 is 0 mod 8)
            for (int nt = 0; nt < 13; ++nt) {
                int kb = (nt * 16 + l16) * 128 + quad * 16;
                short8 b0 = *(const short8*)((const char*)Ks + (kb ^ sw));
                short8 b1 = *(const short8*)((const char*)Ks + ((kb + 64) ^ sw));
                S[nt] = MFMA16(afrag[0], b0, S[nt]);
                S[nt] = MFMA16(afrag[1], b1, S[nt]);
            }

            for (int nt = 0; nt < 13; ++nt) {
                int key = nt * 16 + l16;
                float mask = (key < NKEY) ? 0.f : -1e30f;
                for (int r = 0; r < 4; ++r) S[nt][r] = S[nt][r] * scale + mask;
            }

            float inv_sum[4];
            for (int r = 0; r < 4; ++r) {
                float m = -1e30f;
                for (int nt = 0; nt < 13; ++nt) m = fmaxf(m, S[nt][r]);
                for (int off = 1; off < 16; off <<= 1) m = fmaxf(m, __shfl_xor(m, off, 64));
                float s = 0.f;
                for (int nt = 0; nt < 13; ++nt) {
                    float e = __expf(S[nt][r] - m);
                    S[nt][r] = e;
                    s += e;
                }
                for (int off = 1; off < 16; off <<= 1) s += __shfl_xor(s, off, 64);
                inv_sum[r] = 1.0f / s;
            }

            // ---- PV: stream P through a double-buffered 16x32 LDS slice.
            floatx4 O[4];
            for (int dt = 0; dt < 4; ++dt) O[dt] = (floatx4){0.f, 0.f, 0.f, 0.f};

            // prologue: write slice 0 (keys 0..31)
            #pragma unroll
            for (int nt2 = 0; nt2 < 2; ++nt2)
                #pragma unroll
                for (int r = 0; r < 4; ++r)
                    Pw[(quad * 4 + r) * PSL + nt2 * 16 + l16] = f2bf(S[nt2][r]);

            for (int ks = 0; ks < 7; ++ks) {
                const short* cur = Pw + (ks & 1) * SLICE_ELS;
                short8 af = *(const short8*)&cur[l16 * PSL + quad * 8];
                short8 bfr_[4];
                #pragma unroll
                for (int dt = 0; dt < 4; ++dt) {
                    int vrow = dt * 16 + l16;
                    int vb = vrow * (VST * 2) + ks * 64 + quad * 16;
                    vb ^= ((vrow >> 3) & 7) << 4;
                    bfr_[dt] = *(const short8*)((const char*)VT + vb);
                }
                if (ks < 6) {   // write next slice; MFMA below hides the latency
                    short* nxt = Pw + ((ks + 1) & 1) * SLICE_ELS;
                    #pragma unroll
                    for (int nt2 = 0; nt2 < 2; ++nt2)
                        #pragma unroll
                        for (int r = 0; r < 4; ++r) {
                            int idx = 2 * (ks + 1) + nt2;
                            nxt[(quad * 4 + r) * PSL + nt2 * 16 + l16] =
                                (idx < 13) ? f2bf(S[idx][r]) : (short)0;
                        }
                }
                #pragma unroll
                for (int dt = 0; dt < 4; ++dt)
                    O[dt] = MFMA16(af, bfr_[dt], O[dt]);
            }

            // ---- O: bounce through LDS -> coalesced full-line stores
            short* Ob = Pw;   // reuse per-wave P area as [16][80]
            #pragma unroll
            for (int dt = 0; dt < 4; ++dt)
                #pragma unroll
                for (int r = 0; r < 4; ++r)
                    Ob[(quad * 4 + r) * 80 + dt * 16 + l16] = f2bf(O[dt][r] * inv_sum[r]);
            int orow = lane >> 2, oseg = lane & 3;
            short8 o0 = *(const short8*)&Ob[orow * 80 + oseg * 16];
            short8 o1 = *(const short8*)&Ob[orow * 80 + oseg * 16 + 8];
            int m = qt * 16 + orow;
            if (m < NPF) {
                short* dst = qk + (basetok + (1 + f * NPF + m)) * QKCOLS + hc + oseg * 16;
                *(short8*)dst = o0;
                *(short8*)(dst + 8) = o1;
            }
        }
    } else {
        // ---------------- CLS attention ----------------
        int cblk = blockIdx.x;
        int h = cblk % NHEAD, b = cblk / NHEAD;
        const size_t basetok = (size_t)b * NTOK;
        const int hc = h * DHEAD;
        int tid = threadIdx.x;
        ClsLds& ca = u.ca;

        if (tid < DHEAD) ca.qs[tid] = bf2f(qk[basetok * QKCOLS + hc + tid]) * 0.125f;
        __syncthreads();

        float lmax = -1e30f;
        for (int j = tid; j < NTOK; j += 256) {
            const short* krow = qk + (basetok + j) * QKCOLS + DIM + hc;
            float s = 0.f;
            #pragma unroll
            for (int c = 0; c < 8; ++c) {
                short8 kv = *(const short8*)(krow + c * 8);
                const float4* qp = (const float4*)&ca.qs[c * 8];
                float4 q0 = qp[0], q1 = qp[1];
                s += q0.x * bf2f(kv[0]); s += q0.y * bf2f(kv[1]);
                s += q0.z * bf2f(kv[2]); s += q0.w * bf2f(kv[3]);
                s += q1.x * bf2f(kv[4]); s += q1.y * bf2f(kv[5]);
                s += q1.z * bf2f(kv[6]); s += q1.w * bf2f(kv[7]);
            }
            ca.sexp[j] = s;
            lmax = fmaxf(lmax, s);
        }
        for (int off = 1; off < 64; off <<= 1) lmax = fmaxf(lmax, __shfl_xor(lmax, off, 64));
        if ((tid & 63) == 0) ca.red[tid >> 6] = lmax;
        __syncthreads();
        float mx = fmaxf(fmaxf(ca.red[0], ca.red[1]), fmaxf(ca.red[2], ca.red[3]));

        float lsum = 0.f;
        for (int j = tid; j < NTOK; j += 256) {
            float e = __expf(ca.sexp[j] - mx);
            ca.sexp[j] = e;
            lsum += e;
        }
        for (int off = 1; off < 64; off <<= 1) lsum += __shfl_xor(lsum, off, 64);
        if ((tid & 63) == 0) ca.red[4 + (tid >> 6)] = lsum;
        __syncthreads();
        float sum = ca.red[4] + ca.red[5] + ca.red[6] + ca.red[7];

        int dd = tid & 63, strip = tid >> 6;
        float acc = 0.f;
        for (int j = strip; j < NTOK; j += 4)
            acc += ca.sexp[j] * bf2f(vsrc[(basetok + j) * DIM + hc + dd]);
        ca.partial[strip][dd] = acc;
        __syncthreads();

        if (tid < DHEAD) {
            float o = (ca.partial[0][tid] + ca.partial[1][tid] +
                       ca.partial[2][tid] + ca.partial[3][tid]) / sum;
            qk[basetok * QKCOLS + hc + tid] = f2bf(o);
        }
    }
}

// ---------------------------------------------------------------------------
extern "C" void kernel_launch(void* const* d_in, const int* in_sizes, int n_in,
                              void* d_out, int out_size, void* d_ws, size_t ws_size,
                              hipStream_t stream) {
    const float* x      = (const float*)d_in[0];   // (B, N, D) fp32
    const float* w_qkv  = (const float*)d_in[1];   // (D, 3D) fp32
    const float* w_proj = (const float*)d_in[2];   // (D, D) fp32
    const float* b_proj = (const float*)d_in[3];   // (D,) fp32
    float* out = (float*)d_out;                    // fp32 output (77.1 MB)

    // d_out doubles as scratch pre-proj: [xbf 38.56 MB | vbuf 38.56 MB]
    short* xbf  = (short*)d_out;
    short* vbuf = (short*)d_out + (size_t)MROWS * DIM;

    // ws: qk bf16 (MROWS x 1536) | wqkvT (2304x768) | wprojT (768x768) = ~82 MB
    const size_t QK_EL     = (size_t)MROWS * QKCOLS;
    const size_t WQKVT_EL  = (size_t)D3 * DIM;
    const size_t WPROJT_EL = (size_t)DIM * DIM;
    const size_t WS_NEEDED = (QK_EL + WQKVT_EL + WPROJT_EL) * sizeof(short);

    if (ws_size < WS_NEEDED) {
        zero_out_k<<<(out_size + 255) / 256, 256, 0, stream>>>(out, out_size);
        return;
    }

    short* qk     = (short*)d_ws;
    short* wqkvT  = qk + QK_EL;
    short* wprojT = wqkvT + WQKVT_EL;

    cvt_bf16_k<<<(MROWS * DIM / 8 + 255) / 256, 256, 0, stream>>>(x, xbf, MROWS * DIM / 8);
    transpose_cvt_k<<<dim3(D3 / 32, DIM / 32), 256, 0, stream>>>(w_qkv, wqkvT, DIM, D3);
    transpose_cvt_k<<<dim3(DIM / 32, DIM / 32), 256, 0, stream>>>(w_proj, wprojT, DIM, DIM);

    // qkv = xbf @ w_qkv ; cols 0..1535 (Q,K) -> qk, cols 1536.. (V) -> vbuf
    {
        int gx = D3 / 256;                       // 9
        int gy = (MROWS + 255) / 256;            // 99
        int nwg = gx * gy;                       // 891
        gemm256<false><<<nwg, 512, 0, stream>>>(
            xbf, DIM, wqkvT, nullptr, qk, QKCOLS, vbuf, DIM, QKCOLS, MROWS, DIM,
            gx, nwg);
    }

    attn_k<<<NFBLK + CLSBLK, 256, 0, stream>>>(qk, vbuf);

    // out = attnout @ w_proj + b_proj (attnout = qk's Q region, lda=1536; fp32 out)
    {
        int gx = DIM / 128;                      // 6
        int gy = (MROWS + 127) / 128;            // 197
        int nwg = gx * gy;                       // 1182
        gemm_lds<true><<<nwg, 256, 0, stream>>>(
            qk, QKCOLS, wprojT, b_proj, out, DIM, nullptr, 0, 2 * DIM /*no split*/,
            MROWS, DIM, gx, nwg);
    }
}

// Round 6
// 439.097 us; speedup vs baseline: 1.1196x; 1.0805x over previous
//
#include <hip/hip_runtime.h>
#include <hip/hip_bf16.h>

// Problem constants (B=16, F=8, NP=196, D=768, H=12)
#define BATCH 16
#define NFRAME 8
#define NPF 196          // tokens per frame
#define DIM 768
#define NHEAD 12
#define DHEAD 64
#define NTOK 1569        // 1 + 8*196
#define MROWS (BATCH * NTOK)   // 25104
#define D3 (3 * DIM)           // 2304
#define NKEY 197         // CLS + frame keys
#define NKP 224          // padded keys for PV (7*32)
#define NKQ 208          // padded keys for QK (13*16)
#define VST 232          // VT LDS row stride in shorts (464 B, 16B-aligned)
#define PSL 40           // P slice row stride in shorts (80 B, 16B-aligned)
#define SLICE_ELS (16 * PSL)   // one 16q x 32key slice (640 shorts = 1280 B)
#define NFBLK (BATCH * NHEAD * NFRAME)   // 1536 frame-attn blocks
#define CLSBLK (BATCH * NHEAD)           // 192 CLS blocks (dispatched FIRST)
// head-major buffer: rows (b*NHEAD+h)*NTOK+tok, 64 shorts each
#define HM_EL ((size_t)BATCH * NHEAD * NTOK * DHEAD)   // 19,279,872 == MROWS*DIM

typedef __attribute__((ext_vector_type(8))) short short8;
typedef __attribute__((ext_vector_type(4))) float floatx4;

#define MFMA16(A, B, C) __builtin_amdgcn_mfma_f32_16x16x32_bf16((A), (B), (C), 0, 0, 0)

__device__ __forceinline__ float bf2f(short s) {
    union { unsigned u; float f; } x;
    x.u = ((unsigned)(unsigned short)s) << 16;
    return x.f;
}
__device__ __forceinline__ short f2bf(float f) {
    union { float f; unsigned u; } x;
    x.f = f;
    unsigned r = x.u + 0x7fffu + ((x.u >> 16) & 1u);  // RNE
    return (short)(r >> 16);
}

// async global(bf16)->LDS, 16 bytes per lane
__device__ __forceinline__ void gld_lds16(const short* g, short* l) {
    __builtin_amdgcn_global_load_lds(
        (const __attribute__((address_space(1))) void*)g,
        (__attribute__((address_space(3))) void*)l, 16, 0, 0);
}

// bijective XCD swizzle (m204)
__device__ __forceinline__ int xcd_swizzle(int d, int nwg) {
    int q = nwg >> 3, r = nwg & 7;
    int xcd = d & 7, j = d >> 3;
    return (xcd < r ? xcd * (q + 1) : r * (q + 1) + (xcd - r) * q) + j;
}

// ---------------------------------------------------------------------------
__global__ __launch_bounds__(256) void zero_out_k(float* __restrict__ out, int n) {
    int i = blockIdx.x * 256 + threadIdx.x;
    if (i < n) out[i] = 0.f;
}

// ---------------------------------------------------------------------------
__global__ __launch_bounds__(256) void cvt_bf16_k(const float* __restrict__ in,
                                                  short* __restrict__ out, int n8) {
    int i = blockIdx.x * 256 + threadIdx.x;
    if (i < n8) {
        const float4* p = (const float4*)(in + (size_t)i * 8);
        float4 u0 = p[0], u1 = p[1];
        short8 t;
        t[0] = f2bf(u0.x); t[1] = f2bf(u0.y); t[2] = f2bf(u0.z); t[3] = f2bf(u0.w);
        t[4] = f2bf(u1.x); t[5] = f2bf(u1.y); t[6] = f2bf(u1.z); t[7] = f2bf(u1.w);
        *(short8*)(out + (size_t)i * 8) = t;
    }
}

// ---------------------------------------------------------------------------
__global__ __launch_bounds__(256) void transpose_cvt_k(const float* __restrict__ in,
                                                       short* __restrict__ out,
                                                       int R, int C) {
    __shared__ float tile[32][33];
    int tx = threadIdx.x & 31, ty = threadIdx.x >> 5;
    int r0 = blockIdx.y * 32, c0 = blockIdx.x * 32;
    for (int i = 0; i < 4; ++i) {
        int r = ty + i * 8;
        tile[r][tx] = in[(size_t)(r0 + r) * C + c0 + tx];
    }
    __syncthreads();
    for (int i = 0; i < 4; ++i) {
        int c = ty + i * 8;
        out[(size_t)(c0 + c) * R + r0 + tx] = f2bf(tile[tx][c]);
    }
}

// ---------------------------------------------------------------------------
// LDS-tiled GEMM (m97 structure, 128x128) — used for the proj GEMM.
// ---------------------------------------------------------------------------
__global__ __launch_bounds__(256) void gemm_proj(const short* __restrict__ A, int lda,
                                                 const short* __restrict__ BT,
                                                 const float* __restrict__ bias,
                                                 float* __restrict__ C, int ldc,
                                                 int M, int K, int gx, int nwg) {
    __shared__ __align__(16) short As[128 * 32];
    __shared__ __align__(16) short Bs[128 * 32];

    int tid = threadIdx.x;
    int lane = tid & 63, wid = tid >> 6;
    int l16 = lane & 15, quad = lane >> 4;
    int wg = xcd_swizzle(blockIdx.x, nwg);
    int n0 = (wg % gx) * 128, m0 = (wg / gx) * 128;
    int wm = (wid & 1) * 64, wn = (wid >> 1) * 64;

    int id0 = tid, id1 = tid + 256;
    int ar0 = id0 >> 2, ak0 = (id0 & 3) * 8;
    int ar1 = id1 >> 2, ak1 = (id1 & 3) * 8;
    int ga0 = m0 + ar0; if (ga0 >= M) ga0 = M - 1;
    int ga1 = m0 + ar1; if (ga1 >= M) ga1 = M - 1;
    const short* Ap0 = A + (size_t)ga0 * lda + ak0;
    const short* Ap1 = A + (size_t)ga1 * lda + ak1;
    const short* Bp0 = BT + (size_t)(n0 + ar0) * K + ak0;
    const short* Bp1 = BT + (size_t)(n0 + ar1) * K + ak1;

    floatx4 acc[4][4];
    for (int mt = 0; mt < 4; ++mt)
        for (int nt = 0; nt < 4; ++nt)
            acc[mt][nt] = (floatx4){0.f, 0.f, 0.f, 0.f};

    for (int k0 = 0; k0 < K; k0 += 32) {
        if (k0) __syncthreads();
        gld_lds16(Ap0 + k0, &As[id0 * 8]);
        gld_lds16(Ap1 + k0, &As[id1 * 8]);
        gld_lds16(Bp0 + k0, &Bs[id0 * 8]);
        gld_lds16(Bp1 + k0, &Bs[id1 * 8]);
        __syncthreads();

        short8 a[4], b[4];
        for (int mt = 0; mt < 4; ++mt)
            a[mt] = *(const short8*)&As[(wm + mt * 16 + l16) * 32 + quad * 8];
        for (int nt = 0; nt < 4; ++nt)
            b[nt] = *(const short8*)&Bs[(wn + nt * 16 + l16) * 32 + quad * 8];
        for (int mt = 0; mt < 4; ++mt)
            for (int nt = 0; nt < 4; ++nt)
                acc[mt][nt] = MFMA16(a[mt], b[nt], acc[mt][nt]);
    }

    for (int mt = 0; mt < 4; ++mt)
        for (int nt = 0; nt < 4; ++nt) {
            int col0 = n0 + wn + nt * 16;
            float bv = bias ? bias[col0 + l16] : 0.f;
            for (int r = 0; r < 4; ++r) {
                int row = m0 + wm + mt * 16 + quad * 4 + r;
                if (row < M)
                    C[(size_t)row * ldc + col0 + l16] = acc[mt][nt][r] + bv;
            }
        }
}

// ---------------------------------------------------------------------------
// 256x256 QKV GEMM, BK=32, 8 waves, 4-slot LDS ring, counted-vmcnt fine-phase
// schedule (r4 structure, unchanged). Epilogue writes Q/K/V HEAD-MAJOR:
// dest row = (b*NHEAD+h)*NTOK + tok, 64 bf16 per row.
// ---------------------------------------------------------------------------
__global__ __launch_bounds__(512, 2) void gemm256_qkv(const short* __restrict__ A, int lda,
                                                      const short* __restrict__ BT,
                                                      short* __restrict__ qh,
                                                      short* __restrict__ kh,
                                                      short* __restrict__ vh,
                                                      int M, int K, int gx, int nwg) {
    __shared__ __align__(16) short lds[4][2][256 * 32];

    const int tid = threadIdx.x;
    const int lane = tid & 63, w = tid >> 6;
    const int l16 = lane & 15, quad = lane >> 4;
    const int wr = w >> 2, wc = w & 3;
    const int wg = xcd_swizzle(blockIdx.x, nwg);
    const int n0 = (wg % gx) * 256, m0 = (wg / gx) * 256;
    const int T = K >> 5;

    const int lcs = ((lane & 3) ^ ((lane >> 3) & 3)) * 8;

    int offA[8], offB[4];
    #pragma unroll
    for (int mt = 0; mt < 8; ++mt) {
        int row = wr * 128 + mt * 16 + l16;
        offA[mt] = row * 32 + (quad ^ ((row >> 1) & 3)) * 8;
    }
    #pragma unroll
    for (int nt = 0; nt < 4; ++nt) {
        int row = wc * 64 + nt * 16 + l16;
        offB[nt] = row * 32 + (quad ^ ((row >> 1) & 3)) * 8;
    }

    floatx4 acc[8][4];
    #pragma unroll
    for (int mt = 0; mt < 8; ++mt)
        #pragma unroll
        for (int nt = 0; nt < 4; ++nt)
            acc[mt][nt] = (floatx4){0.f, 0.f, 0.f, 0.f};

    for (int u = 0; u < 3; ++u) {
        const int ss = u, kst = u * 32;
        #pragma unroll
        for (int j = 0; j < 2; ++j) {
            int row = (w << 5) + (j << 4) + (lane >> 2);
            int gr = m0 + row; if (gr >= M) gr = M - 1;
            gld_lds16(A + (size_t)gr * lda + kst + lcs,
                      &lds[ss][0][((w << 7) + (j << 6) + lane) * 8]);
        }
        #pragma unroll
        for (int j = 0; j < 2; ++j) {
            int row = (w << 5) + (j << 4) + (lane >> 2);
            gld_lds16(BT + (size_t)(n0 + row) * K + kst + lcs,
                      &lds[ss][1][((w << 7) + (j << 6) + lane) * 8]);
        }
    }
    asm volatile("s_waitcnt vmcnt(8)" ::: "memory");
    __builtin_amdgcn_s_barrier();

    for (int t = 0; t < T; ++t) {
        const int slot = t & 3;
        const int ss = (t + 3) & 3;
        const int kst = (t + 3) << 5;
        const bool do_stage = (t + 3) < T;
        const short* baseA = &lds[slot][0][0];
        const short* baseB = &lds[slot][1][0];

        short8 bfr[4], afr[4];

        // phase 0
        #pragma unroll
        for (int nt = 0; nt < 4; ++nt) bfr[nt] = *(const short8*)(baseB + offB[nt]);
        #pragma unroll
        for (int mt = 0; mt < 4; ++mt) afr[mt] = *(const short8*)(baseA + offA[mt]);
        if (do_stage) {
            #pragma unroll
            for (int j = 0; j < 2; ++j) {
                int row = (w << 5) + (j << 4) + (lane >> 2);
                int gr = m0 + row; if (gr >= M) gr = M - 1;
                gld_lds16(A + (size_t)gr * lda + kst + lcs,
                          &lds[ss][0][((w << 7) + (j << 6) + lane) * 8]);
            }
        }
        __builtin_amdgcn_s_barrier();
        asm volatile("s_waitcnt lgkmcnt(0)" ::: "memory");
        __builtin_amdgcn_sched_barrier(0);
        __builtin_amdgcn_s_setprio(1);
        #pragma unroll
        for (int mt = 0; mt < 4; ++mt)
            #pragma unroll
            for (int nt = 0; nt < 4; ++nt)
                acc[mt][nt] = MFMA16(afr[mt], bfr[nt], acc[mt][nt]);
        __builtin_amdgcn_s_setprio(0);
        __builtin_amdgcn_s_barrier();

        // phase 1
        #pragma unroll
        for (int mt = 0; mt < 4; ++mt) afr[mt] = *(const short8*)(baseA + offA[4 + mt]);
        if (do_stage) {
            #pragma unroll
            for (int j = 0; j < 2; ++j) {
                int row = (w << 5) + (j << 4) + (lane >> 2);
                gld_lds16(BT + (size_t)(n0 + row) * K + kst + lcs,
                          &lds[ss][1][((w << 7) + (j << 6) + lane) * 8]);
            }
        }
        __builtin_amdgcn_s_barrier();
        asm volatile("s_waitcnt lgkmcnt(0)" ::: "memory");
        __builtin_amdgcn_sched_barrier(0);
        __builtin_amdgcn_s_setprio(1);
        #pragma unroll
        for (int mt = 0; mt < 4; ++mt)
            #pragma unroll
            for (int nt = 0; nt < 4; ++nt)
                acc[4 + mt][nt] = MFMA16(afr[mt], bfr[nt], acc[4 + mt][nt]);
        __builtin_amdgcn_s_setprio(0);
        if (t + 1 < T) {
            if (t + 3 < T)      asm volatile("s_waitcnt vmcnt(8)" ::: "memory");
            else if (t + 2 < T) asm volatile("s_waitcnt vmcnt(4)" ::: "memory");
            else                asm volatile("s_waitcnt vmcnt(0)" ::: "memory");
        }
        __builtin_amdgcn_s_barrier();
    }

    // ---- epilogue: head-major 3-way split store
    #pragma unroll
    for (int mt = 0; mt < 8; ++mt)
        #pragma unroll
        for (int nt = 0; nt < 4; ++nt) {
            int col0 = n0 + wc * 64 + nt * 16;
            int part = col0 / DIM;               // 0=Q 1=K 2=V (wave-uniform)
            int within = col0 - part * DIM;
            int h = within >> 6, d0 = within & 63;
            short* base = (part == 0) ? qh : (part == 1) ? kh : vh;
            #pragma unroll
            for (int r = 0; r < 4; ++r) {
                int row = m0 + wr * 128 + mt * 16 + quad * 4 + r;
                if (row < M) {
                    int bb = row / NTOK, tk = row - bb * NTOK;
                    base[((size_t)(bb * NHEAD + h) * NTOK + tk) * DHEAD + d0 + l16] =
                        f2bf(acc[mt][nt][r]);
                }
            }
        }
}

// ---------------------------------------------------------------------------
// Merged attention. Head-major inputs q/k/v [(b*h)][tok][64]; output O into
// dense token-major obuf [b*tok][768].
// Blocks 0..191: CLS. Blocks 192..1727: frame attention.
// K staged fully async via gld_lds16 (linear dest, XOR-preswizzled source).
// ---------------------------------------------------------------------------
struct FrameLds {
    short K[NKQ * DHEAD];           // 26624 B, [key][d], 16B-chunk XOR swizzle
    short VT[DHEAD * VST];          // 29696 B, [d][key] swizzled
    short P[4][2 * SLICE_ELS];      // 10240 B, per-wave P slices / O bounce
};
struct ClsLds {
    float qs[DHEAD];
    float sexp[NTOK];
    float red[8];
    float partial[4][DHEAD];
};
union AttnLds {
    FrameLds fa;
    ClsLds ca;
};

__global__ __launch_bounds__(256, 2) void attn_k(const short* __restrict__ q_hm,
                                                 const short* __restrict__ k_hm,
                                                 const short* __restrict__ v_hm,
                                                 short* __restrict__ obuf) {
    __shared__ __align__(16) AttnLds u;

    if (blockIdx.x >= CLSBLK) {
        // ---------------- frame attention ----------------
        int blk = blockIdx.x - CLSBLK;
        int f = blk & 7;
        int h = (blk >> 3) % NHEAD;
        int b = blk / (NHEAD * NFRAME);
        int lane = threadIdx.x & 63, wid = threadIdx.x >> 6;
        int l16 = lane & 15, quad = lane >> 4;
        const size_t hmrow = (size_t)(b * NHEAD + h) * NTOK;   // row base in hm bufs
        short* Ks = u.fa.K;
        short* VT = u.fa.VT;
        short* Pw = u.fa.P[wid];
        int tid = threadIdx.x;

        // ---- K staging: fully async, linear LDS dest, source pre-XOR-swizzled.
        // LDS[row][dc] (16B chunks dc=0..7) = K[tok(row)][dc ^ (row&7)]
        const short* kbase = k_hm + hmrow * DHEAD;
        #pragma unroll
        for (int p = 0; p < 6; ++p) {
            int c = p * 256 + tid;            // rows 0..191
            int row = c >> 3, dc = c & 7;
            int tok = (row == 0) ? 0 : f * NPF + row;
            gld_lds16(kbase + (size_t)tok * DHEAD + ((dc ^ (row & 7)) * 8), &Ks[c * 8]);
        }
        if (tid < 128) {                      // rows 192..207 (pad rows -> tok 0, masked)
            int c = 1536 + tid;
            int row = c >> 3, dc = c & 7;
            int tok = (row <= 196) ? f * NPF + row : 0;
            gld_lds16(kbase + (size_t)tok * DHEAD + ((dc ^ (row & 7)) * 8), &Ks[c * 8]);
        }

        // ---- V staging: dense coalesced loads, swizzled transpose writes
        const short* vbase = v_hm + hmrow * DHEAD;
        for (int c = tid; c < NKP * 8; c += 256) {
            int j = c >> 3, dc = c & 7;
            short8 v = (short8){0, 0, 0, 0, 0, 0, 0, 0};
            if (j < NKEY) {
                int tok = (j == 0) ? 0 : f * NPF + j;
                v = *(const short8*)(vbase + (size_t)tok * DHEAD + dc * 8);
            }
            #pragma unroll
            for (int t = 0; t < 8; ++t) {
                int row = dc * 8 + t;
                int wb = row * (VST * 2) + j * 2;
                wb ^= (dc & 7) << 4;
                *(short*)((char*)VT + wb) = v[t];
            }
        }
        __syncthreads();   // drains vmcnt (gld_lds) + lgkm; the only barrier

        const float scale = 0.125f;
        const short* qbase = q_hm + hmrow * DHEAD;

        for (int qt = wid; qt < 13; qt += 4) {
            floatx4 S[13];
            for (int nt = 0; nt < 13; ++nt) S[nt] = (floatx4){0.f, 0.f, 0.f, 0.f};

            int qm = qt * 16 + l16;
            if (qm > 195) qm = 195;
            int qtok = 1 + f * NPF + qm;
            const short* qrow = qbase + (size_t)qtok * DHEAD;
            short8 afrag[2];
            afrag[0] = *(const short8*)(qrow + quad * 8);
            afrag[1] = *(const short8*)(qrow + 32 + quad * 8);

            int sw = (l16 & 7) << 4;
            for (int nt = 0; nt < 13; ++nt) {
                int kb = (nt * 16 + l16) * 128 + quad * 16;
                short8 b0 = *(const short8*)((const char*)Ks + (kb ^ sw));
                short8 b1 = *(const short8*)((const char*)Ks + ((kb + 64) ^ sw));
                S[nt] = MFMA16(afrag[0], b0, S[nt]);
                S[nt] = MFMA16(afrag[1], b1, S[nt]);
            }

            for (int nt = 0; nt < 13; ++nt) {
                int key = nt * 16 + l16;
                float mask = (key < NKEY) ? 0.f : -1e30f;
                for (int r = 0; r < 4; ++r) S[nt][r] = S[nt][r] * scale + mask;
            }

            float inv_sum[4];
            for (int r = 0; r < 4; ++r) {
                float m = -1e30f;
                for (int nt = 0; nt < 13; ++nt) m = fmaxf(m, S[nt][r]);
                for (int off = 1; off < 16; off <<= 1) m = fmaxf(m, __shfl_xor(m, off, 64));
                float s = 0.f;
                for (int nt = 0; nt < 13; ++nt) {
                    float e = __expf(S[nt][r] - m);
                    S[nt][r] = e;
                    s += e;
                }
                for (int off = 1; off < 16; off <<= 1) s += __shfl_xor(s, off, 64);
                inv_sum[r] = 1.0f / s;
            }

            floatx4 O[4];
            for (int dt = 0; dt < 4; ++dt) O[dt] = (floatx4){0.f, 0.f, 0.f, 0.f};

            #pragma unroll
            for (int nt2 = 0; nt2 < 2; ++nt2)
                #pragma unroll
                for (int r = 0; r < 4; ++r)
                    Pw[(quad * 4 + r) * PSL + nt2 * 16 + l16] = f2bf(S[nt2][r]);

            for (int ks = 0; ks < 7; ++ks) {
                const short* cur = Pw + (ks & 1) * SLICE_ELS;
                short8 af = *(const short8*)&cur[l16 * PSL + quad * 8];
                short8 bfr_[4];
                #pragma unroll
                for (int dt = 0; dt < 4; ++dt) {
                    int vrow = dt * 16 + l16;
                    int vb = vrow * (VST * 2) + ks * 64 + quad * 16;
                    vb ^= ((vrow >> 3) & 7) << 4;
                    bfr_[dt] = *(const short8*)((const char*)VT + vb);
                }
                if (ks < 6) {
                    short* nxt = Pw + ((ks + 1) & 1) * SLICE_ELS;
                    #pragma unroll
                    for (int nt2 = 0; nt2 < 2; ++nt2)
                        #pragma unroll
                        for (int r = 0; r < 4; ++r) {
                            int idx = 2 * (ks + 1) + nt2;
                            nxt[(quad * 4 + r) * PSL + nt2 * 16 + l16] =
                                (idx < 13) ? f2bf(S[idx][r]) : (short)0;
                        }
                }
                #pragma unroll
                for (int dt = 0; dt < 4; ++dt)
                    O[dt] = MFMA16(af, bfr_[dt], O[dt]);
            }

            // ---- O: LDS bounce -> coalesced stores into dense obuf
            short* Ob = Pw;
            #pragma unroll
            for (int dt = 0; dt < 4; ++dt)
                #pragma unroll
                for (int r = 0; r < 4; ++r)
                    Ob[(quad * 4 + r) * 80 + dt * 16 + l16] = f2bf(O[dt][r] * inv_sum[r]);
            int orow = lane >> 2, oseg = lane & 3;
            short8 o0 = *(const short8*)&Ob[orow * 80 + oseg * 16];
            short8 o1 = *(const short8*)&Ob[orow * 80 + oseg * 16 + 8];
            int m = qt * 16 + orow;
            if (m < NPF) {
                int tok = 1 + f * NPF + m;
                short* dst = obuf + ((size_t)b * NTOK + tok) * DIM + h * DHEAD + oseg * 16;
                *(short8*)dst = o0;
                *(short8*)(dst + 8) = o1;
            }
        }
    } else {
        // ---------------- CLS attention ----------------
        int cblk = blockIdx.x;
        int h = cblk % NHEAD, b = cblk / NHEAD;
        const size_t hmrow = (size_t)(b * NHEAD + h) * NTOK;
        int tid = threadIdx.x;
        ClsLds& ca = u.ca;

        if (tid < DHEAD) ca.qs[tid] = bf2f(q_hm[hmrow * DHEAD + tid]) * 0.125f;
        __syncthreads();

        const short* kb = k_hm + hmrow * DHEAD;
        float lmax = -1e30f;
        for (int j = tid; j < NTOK; j += 256) {
            const short* krow = kb + (size_t)j * DHEAD;
            float s = 0.f;
            #pragma unroll
            for (int c = 0; c < 8; ++c) {
                short8 kv = *(const short8*)(krow + c * 8);
                const float4* qp = (const float4*)&ca.qs[c * 8];
                float4 q0 = qp[0], q1 = qp[1];
                s += q0.x * bf2f(kv[0]); s += q0.y * bf2f(kv[1]);
                s += q0.z * bf2f(kv[2]); s += q0.w * bf2f(kv[3]);
                s += q1.x * bf2f(kv[4]); s += q1.y * bf2f(kv[5]);
                s += q1.z * bf2f(kv[6]); s += q1.w * bf2f(kv[7]);
            }
            ca.sexp[j] = s;
            lmax = fmaxf(lmax, s);
        }
        for (int off = 1; off < 64; off <<= 1) lmax = fmaxf(lmax, __shfl_xor(lmax, off, 64));
        if ((tid & 63) == 0) ca.red[tid >> 6] = lmax;
        __syncthreads();
        float mx = fmaxf(fmaxf(ca.red[0], ca.red[1]), fmaxf(ca.red[2], ca.red[3]));

        float lsum = 0.f;
        for (int j = tid; j < NTOK; j += 256) {
            float e = __expf(ca.sexp[j] - mx);
            ca.sexp[j] = e;
            lsum += e;
        }
        for (int off = 1; off < 64; off <<= 1) lsum += __shfl_xor(lsum, off, 64);
        if ((tid & 63) == 0) ca.red[4 + (tid >> 6)] = lsum;
        __syncthreads();
        float sum = ca.red[4] + ca.red[5] + ca.red[6] + ca.red[7];

        const short* vb = v_hm + hmrow * DHEAD;
        int dd = tid & 63, strip = tid >> 6;
        float acc = 0.f;
        for (int j = strip; j < NTOK; j += 4)
            acc += ca.sexp[j] * bf2f(vb[(size_t)j * DHEAD + dd]);
        ca.partial[strip][dd] = acc;
        __syncthreads();

        if (tid < DHEAD) {
            float o = (ca.partial[0][tid] + ca.partial[1][tid] +
                       ca.partial[2][tid] + ca.partial[3][tid]) / sum;
            obuf[(size_t)b * NTOK * DIM + h * DHEAD + tid] = f2bf(o);
        }
    }
}

// ---------------------------------------------------------------------------
extern "C" void kernel_launch(void* const* d_in, const int* in_sizes, int n_in,
                              void* d_out, int out_size, void* d_ws, size_t ws_size,
                              hipStream_t stream) {
    const float* x      = (const float*)d_in[0];
    const float* w_qkv  = (const float*)d_in[1];
    const float* w_proj = (const float*)d_in[2];
    const float* b_proj = (const float*)d_in[3];
    float* out = (float*)d_out;

    // ws layout: [xbf (reused as obuf) | q_hm | wqkvT | wprojT]  (~81.8 MB)
    const size_t WQKVT_EL  = (size_t)D3 * DIM;
    const size_t WPROJT_EL = (size_t)DIM * DIM;
    const size_t WS_NEEDED = (2 * HM_EL + WQKVT_EL + WPROJT_EL) * sizeof(short);

    if (ws_size < WS_NEEDED) {
        zero_out_k<<<(out_size + 255) / 256, 256, 0, stream>>>(out, out_size);
        return;
    }

    short* xbf    = (short*)d_ws;            // MROWS*DIM == HM_EL elements
    short* obuf   = xbf;                     // reuses xbf (dead after QKV GEMM)
    short* q_hm   = xbf + HM_EL;
    short* wqkvT  = q_hm + HM_EL;
    short* wprojT = wqkvT + WQKVT_EL;

    // d_out pre-proj: [k_hm | v_hm] (2*HM_EL shorts == out_size bytes exactly)
    short* k_hm = (short*)d_out;
    short* v_hm = k_hm + HM_EL;

    cvt_bf16_k<<<(MROWS * DIM / 8 + 255) / 256, 256, 0, stream>>>(x, xbf, MROWS * DIM / 8);
    transpose_cvt_k<<<dim3(D3 / 32, DIM / 32), 256, 0, stream>>>(w_qkv, wqkvT, DIM, D3);
    transpose_cvt_k<<<dim3(DIM / 32, DIM / 32), 256, 0, stream>>>(w_proj, wprojT, DIM, DIM);

    // qkv = xbf @ w_qkv -> head-major q/k/v
    {
        int gx = D3 / 256;                       // 9
        int gy = (MROWS + 255) / 256;            // 99
        int nwg = gx * gy;
        gemm256_qkv<<<nwg, 512, 0, stream>>>(
            xbf, DIM, wqkvT, q_hm, k_hm, v_hm, MROWS, DIM, gx, nwg);
    }

    attn_k<<<NFBLK + CLSBLK, 256, 0, stream>>>(q_hm, k_hm, v_hm, obuf);

    // out = obuf @ w_proj + b_proj
    {
        int gx = DIM / 128;                      // 6
        int gy = (MROWS + 127) / 128;            // 197
        int nwg = gx * gy;
        gemm_proj<<<nwg, 256, 0, stream>>>(
            obuf, DIM, wprojT, b_proj, out, DIM, MROWS, DIM, gx, nwg);
    }
}

// Round 7
// 432.638 us; speedup vs baseline: 1.1363x; 1.0149x over previous
//
#include <hip/hip_runtime.h>
#include <hip/hip_bf16.h>

// Problem constants (B=16, F=8, NP=196, D=768, H=12)
#define BATCH 16
#define NFRAME 8
#define NPF 196          // tokens per frame
#define DIM 768
#define NHEAD 12
#define DHEAD 64
#define NTOK 1569        // 1 + 8*196
#define MROWS (BATCH * NTOK)   // 25104
#define D3 (3 * DIM)           // 2304
#define NKEY 197         // CLS + frame keys
#define NKP 224          // padded keys for PV (7*32)
#define NKQ 208          // padded keys for QK (13*16)
#define VST 232          // VT LDS row stride in shorts (464 B, 16B-aligned)
#define PSL 40           // P slice row stride in shorts (80 B, 16B-aligned)
#define SLICE_ELS (16 * PSL)   // one 16q x 32key slice (640 shorts = 1280 B)
#define NFBLK (BATCH * NHEAD * NFRAME)   // 1536 frame-attn blocks
#define CLSBLK (BATCH * NHEAD)           // 192 CLS blocks (dispatched FIRST)
// head-major buffer: rows (b*NHEAD+h)*NTOK+tok, 64 shorts each
#define HM_EL ((size_t)BATCH * NHEAD * NTOK * DHEAD)   // 19,279,872 == MROWS*DIM

// merged prep kernel block ranges
#define CVT_BLKS (MROWS * DIM / 8 / 256)       // 9414 (exact)
#define TRA_GX (D3 / 32)                       // 72
#define TRA_BLKS (TRA_GX * (DIM / 32))         // 1728
#define TRB_GX (DIM / 32)                      // 24
#define TRB_BLKS (TRB_GX * (DIM / 32))         // 576

typedef __attribute__((ext_vector_type(8))) short short8;
typedef __attribute__((ext_vector_type(4))) float floatx4;

#define MFMA16(A, B, C) __builtin_amdgcn_mfma_f32_16x16x32_bf16((A), (B), (C), 0, 0, 0)

__device__ __forceinline__ float bf2f(short s) {
    union { unsigned u; float f; } x;
    x.u = ((unsigned)(unsigned short)s) << 16;
    return x.f;
}
__device__ __forceinline__ short f2bf(float f) {
    union { float f; unsigned u; } x;
    x.f = f;
    unsigned r = x.u + 0x7fffu + ((x.u >> 16) & 1u);  // RNE
    return (short)(r >> 16);
}

// async global(bf16)->LDS, 16 bytes per lane
__device__ __forceinline__ void gld_lds16(const short* g, short* l) {
    __builtin_amdgcn_global_load_lds(
        (const __attribute__((address_space(1))) void*)g,
        (__attribute__((address_space(3))) void*)l, 16, 0, 0);
}

// bijective XCD swizzle (m204)
__device__ __forceinline__ int xcd_swizzle(int d, int nwg) {
    int q = nwg >> 3, r = nwg & 7;
    int xcd = d & 7, j = d >> 3;
    return (xcd < r ? xcd * (q + 1) : r * (q + 1) + (xcd - r) * q) + j;
}

// ---------------------------------------------------------------------------
__global__ __launch_bounds__(256) void zero_out_k(float* __restrict__ out, int n) {
    int i = blockIdx.x * 256 + threadIdx.x;
    if (i < n) out[i] = 0.f;
}

// ---------------------------------------------------------------------------
// Merged prep: fp32->bf16 convert of x, plus both weight transposes,
// in a single dispatch (3 block ranges).
// ---------------------------------------------------------------------------
__device__ __forceinline__ void transpose_tile(const float* __restrict__ in,
                                               short* __restrict__ out,
                                               int R, int C, int bx, int by,
                                               float (*tile)[33]) {
    int tx = threadIdx.x & 31, ty = threadIdx.x >> 5;
    int r0 = by * 32, c0 = bx * 32;
    for (int i = 0; i < 4; ++i) {
        int r = ty + i * 8;
        tile[r][tx] = in[(size_t)(r0 + r) * C + c0 + tx];
    }
    __syncthreads();
    for (int i = 0; i < 4; ++i) {
        int c = ty + i * 8;
        out[(size_t)(c0 + c) * R + r0 + tx] = f2bf(tile[tx][c]);
    }
}

__global__ __launch_bounds__(256) void prep_k(const float* __restrict__ x,
                                              short* __restrict__ xbf,
                                              const float* __restrict__ w_qkv,
                                              short* __restrict__ wqkvT,
                                              const float* __restrict__ w_proj,
                                              short* __restrict__ wprojT) {
    __shared__ float tile[32][33];
    int bid = blockIdx.x;
    if (bid < CVT_BLKS) {
        int i = bid * 256 + threadIdx.x;
        const float4* p = (const float4*)(x + (size_t)i * 8);
        float4 u0 = p[0], u1 = p[1];
        short8 t;
        t[0] = f2bf(u0.x); t[1] = f2bf(u0.y); t[2] = f2bf(u0.z); t[3] = f2bf(u0.w);
        t[4] = f2bf(u1.x); t[5] = f2bf(u1.y); t[6] = f2bf(u1.z); t[7] = f2bf(u1.w);
        *(short8*)(xbf + (size_t)i * 8) = t;
    } else if (bid < CVT_BLKS + TRA_BLKS) {
        int id = bid - CVT_BLKS;
        transpose_tile(w_qkv, wqkvT, DIM, D3, id % TRA_GX, id / TRA_GX, tile);
    } else {
        int id = bid - CVT_BLKS - TRA_BLKS;
        transpose_tile(w_proj, wprojT, DIM, DIM, id % TRB_GX, id / TRB_GX, tile);
    }
}

// ---------------------------------------------------------------------------
// LDS-tiled GEMM (m97 structure, 128x128) — used for the proj GEMM.
// ---------------------------------------------------------------------------
__global__ __launch_bounds__(256) void gemm_proj(const short* __restrict__ A, int lda,
                                                 const short* __restrict__ BT,
                                                 const float* __restrict__ bias,
                                                 float* __restrict__ C, int ldc,
                                                 int M, int K, int gx, int nwg) {
    __shared__ __align__(16) short As[128 * 32];
    __shared__ __align__(16) short Bs[128 * 32];

    int tid = threadIdx.x;
    int lane = tid & 63, wid = tid >> 6;
    int l16 = lane & 15, quad = lane >> 4;
    int wg = xcd_swizzle(blockIdx.x, nwg);
    int n0 = (wg % gx) * 128, m0 = (wg / gx) * 128;
    int wm = (wid & 1) * 64, wn = (wid >> 1) * 64;

    int id0 = tid, id1 = tid + 256;
    int ar0 = id0 >> 2, ak0 = (id0 & 3) * 8;
    int ar1 = id1 >> 2, ak1 = (id1 & 3) * 8;
    int ga0 = m0 + ar0; if (ga0 >= M) ga0 = M - 1;
    int ga1 = m0 + ar1; if (ga1 >= M) ga1 = M - 1;
    const short* Ap0 = A + (size_t)ga0 * lda + ak0;
    const short* Ap1 = A + (size_t)ga1 * lda + ak1;
    const short* Bp0 = BT + (size_t)(n0 + ar0) * K + ak0;
    const short* Bp1 = BT + (size_t)(n0 + ar1) * K + ak1;

    floatx4 acc[4][4];
    for (int mt = 0; mt < 4; ++mt)
        for (int nt = 0; nt < 4; ++nt)
            acc[mt][nt] = (floatx4){0.f, 0.f, 0.f, 0.f};

    for (int k0 = 0; k0 < K; k0 += 32) {
        if (k0) __syncthreads();
        gld_lds16(Ap0 + k0, &As[id0 * 8]);
        gld_lds16(Ap1 + k0, &As[id1 * 8]);
        gld_lds16(Bp0 + k0, &Bs[id0 * 8]);
        gld_lds16(Bp1 + k0, &Bs[id1 * 8]);
        __syncthreads();

        short8 a[4], b[4];
        for (int mt = 0; mt < 4; ++mt)
            a[mt] = *(const short8*)&As[(wm + mt * 16 + l16) * 32 + quad * 8];
        for (int nt = 0; nt < 4; ++nt)
            b[nt] = *(const short8*)&Bs[(wn + nt * 16 + l16) * 32 + quad * 8];
        for (int mt = 0; mt < 4; ++mt)
            for (int nt = 0; nt < 4; ++nt)
                acc[mt][nt] = MFMA16(a[mt], b[nt], acc[mt][nt]);
    }

    for (int mt = 0; mt < 4; ++mt)
        for (int nt = 0; nt < 4; ++nt) {
            int col0 = n0 + wn + nt * 16;
            float bv = bias ? bias[col0 + l16] : 0.f;
            for (int r = 0; r < 4; ++r) {
                int row = m0 + wm + mt * 16 + quad * 4 + r;
                if (row < M)
                    C[(size_t)row * ldc + col0 + l16] = acc[mt][nt][r] + bv;
            }
        }
}

// ---------------------------------------------------------------------------
// 256x256 QKV GEMM, BK=32, 8 waves, 4-slot LDS ring, counted-vmcnt pipeline.
// Round-7 schedule: ONE barrier per K-tile; all 12 fragment ds_reads issued
// up front with NO manual lgkmcnt — the compiler emits counted lgkm waits so
// the last 4 reads drain under the first 16 MFMAs (read/MFMA overlap).
// Safety: reads of slot s complete (consumed) before the tile-end barrier;
// stage into slot (t+3)&3 == (t-1)&3 happens a full tile after that slot's
// reads retired. vmcnt chain (8/4/0) identical to r4/r6 (verified).
// ---------------------------------------------------------------------------
__global__ __launch_bounds__(512, 2) void gemm256_qkv(const short* __restrict__ A, int lda,
                                                      const short* __restrict__ BT,
                                                      short* __restrict__ qh,
                                                      short* __restrict__ kh,
                                                      short* __restrict__ vh,
                                                      int M, int K, int gx, int nwg) {
    __shared__ __align__(16) short lds[4][2][256 * 32];

    const int tid = threadIdx.x;
    const int lane = tid & 63, w = tid >> 6;
    const int l16 = lane & 15, quad = lane >> 4;
    const int wr = w >> 2, wc = w & 3;
    const int wg = xcd_swizzle(blockIdx.x, nwg);
    const int n0 = (wg % gx) * 256, m0 = (wg / gx) * 256;
    const int T = K >> 5;

    const int lcs = ((lane & 3) ^ ((lane >> 3) & 3)) * 8;

    int offA[8], offB[4];
    #pragma unroll
    for (int mt = 0; mt < 8; ++mt) {
        int row = wr * 128 + mt * 16 + l16;
        offA[mt] = row * 32 + (quad ^ ((row >> 1) & 3)) * 8;
    }
    #pragma unroll
    for (int nt = 0; nt < 4; ++nt) {
        int row = wc * 64 + nt * 16 + l16;
        offB[nt] = row * 32 + (quad ^ ((row >> 1) & 3)) * 8;
    }

    floatx4 acc[8][4];
    #pragma unroll
    for (int mt = 0; mt < 8; ++mt)
        #pragma unroll
        for (int nt = 0; nt < 4; ++nt)
            acc[mt][nt] = (floatx4){0.f, 0.f, 0.f, 0.f};

    // ---- prologue: stage K-tiles 0,1,2 into slots 0,1,2
    for (int u = 0; u < 3; ++u) {
        const int ss = u, kst = u * 32;
        #pragma unroll
        for (int j = 0; j < 2; ++j) {
            int row = (w << 5) + (j << 4) + (lane >> 2);
            int gr = m0 + row; if (gr >= M) gr = M - 1;
            gld_lds16(A + (size_t)gr * lda + kst + lcs,
                      &lds[ss][0][((w << 7) + (j << 6) + lane) * 8]);
        }
        #pragma unroll
        for (int j = 0; j < 2; ++j) {
            int row = (w << 5) + (j << 4) + (lane >> 2);
            gld_lds16(BT + (size_t)(n0 + row) * K + kst + lcs,
                      &lds[ss][1][((w << 7) + (j << 6) + lane) * 8]);
        }
    }
    asm volatile("s_waitcnt vmcnt(8)" ::: "memory");   // tile 0 landed
    __builtin_amdgcn_s_barrier();

    for (int t = 0; t < T; ++t) {
        const int slot = t & 3;
        const int ss = (t + 3) & 3;
        const int kst = (t + 3) << 5;
        const bool do_stage = (t + 3) < T;
        const short* baseA = &lds[slot][0][0];
        const short* baseB = &lds[slot][1][0];

        // stage tile t+3 first (max global-latency overlap window)
        if (do_stage) {
            #pragma unroll
            for (int j = 0; j < 2; ++j) {
                int row = (w << 5) + (j << 4) + (lane >> 2);
                int gr = m0 + row; if (gr >= M) gr = M - 1;
                gld_lds16(A + (size_t)gr * lda + kst + lcs,
                          &lds[ss][0][((w << 7) + (j << 6) + lane) * 8]);
            }
            #pragma unroll
            for (int j = 0; j < 2; ++j) {
                int row = (w << 5) + (j << 4) + (lane >> 2);
                gld_lds16(BT + (size_t)(n0 + row) * K + kst + lcs,
                          &lds[ss][1][((w << 7) + (j << 6) + lane) * 8]);
            }
        }

        // issue ALL fragment reads; compiler emits counted lgkm waits so the
        // afr1 reads drain under the first MFMA half.
        short8 bfr[4], afr0[4], afr1[4];
        #pragma unroll
        for (int nt = 0; nt < 4; ++nt) bfr[nt] = *(const short8*)(baseB + offB[nt]);
        #pragma unroll
        for (int mt = 0; mt < 4; ++mt) afr0[mt] = *(const short8*)(baseA + offA[mt]);
        #pragma unroll
        for (int mt = 0; mt < 4; ++mt) afr1[mt] = *(const short8*)(baseA + offA[4 + mt]);

        __builtin_amdgcn_s_setprio(1);
        #pragma unroll
        for (int mt = 0; mt < 4; ++mt)
            #pragma unroll
            for (int nt = 0; nt < 4; ++nt)
                acc[mt][nt] = MFMA16(afr0[mt], bfr[nt], acc[mt][nt]);
        #pragma unroll
        for (int mt = 0; mt < 4; ++mt)
            #pragma unroll
            for (int nt = 0; nt < 4; ++nt)
                acc[4 + mt][nt] = MFMA16(afr1[mt], bfr[nt], acc[4 + mt][nt]);
        __builtin_amdgcn_s_setprio(0);

        // counted vmcnt: confirm tile t+1 landed (never 0 in steady state)
        if (t + 1 < T) {
            if (t + 3 < T)      asm volatile("s_waitcnt vmcnt(8)" ::: "memory");
            else if (t + 2 < T) asm volatile("s_waitcnt vmcnt(4)" ::: "memory");
            else                asm volatile("s_waitcnt vmcnt(0)" ::: "memory");
        }
        __builtin_amdgcn_s_barrier();        // the only barrier per K-tile
    }

    // ---- epilogue: head-major 3-way split store
    #pragma unroll
    for (int mt = 0; mt < 8; ++mt)
        #pragma unroll
        for (int nt = 0; nt < 4; ++nt) {
            int col0 = n0 + wc * 64 + nt * 16;
            int part = col0 / DIM;               // 0=Q 1=K 2=V (wave-uniform)
            int within = col0 - part * DIM;
            int h = within >> 6, d0 = within & 63;
            short* base = (part == 0) ? qh : (part == 1) ? kh : vh;
            #pragma unroll
            for (int r = 0; r < 4; ++r) {
                int row = m0 + wr * 128 + mt * 16 + quad * 4 + r;
                if (row < M) {
                    int bb = row / NTOK, tk = row - bb * NTOK;
                    base[((size_t)(bb * NHEAD + h) * NTOK + tk) * DHEAD + d0 + l16] =
                        f2bf(acc[mt][nt][r]);
                }
            }
        }
}

// ---------------------------------------------------------------------------
// Merged attention (unchanged from round 6). Head-major q/k/v in, dense
// token-major obuf out.
// ---------------------------------------------------------------------------
struct FrameLds {
    short K[NKQ * DHEAD];           // 26624 B, [key][d], 16B-chunk XOR swizzle
    short VT[DHEAD * VST];          // 29696 B, [d][key] swizzled
    short P[4][2 * SLICE_ELS];      // 10240 B, per-wave P slices / O bounce
};
struct ClsLds {
    float qs[DHEAD];
    float sexp[NTOK];
    float red[8];
    float partial[4][DHEAD];
};
union AttnLds {
    FrameLds fa;
    ClsLds ca;
};

__global__ __launch_bounds__(256, 2) void attn_k(const short* __restrict__ q_hm,
                                                 const short* __restrict__ k_hm,
                                                 const short* __restrict__ v_hm,
                                                 short* __restrict__ obuf) {
    __shared__ __align__(16) AttnLds u;

    if (blockIdx.x >= CLSBLK) {
        // ---------------- frame attention ----------------
        int blk = blockIdx.x - CLSBLK;
        int f = blk & 7;
        int h = (blk >> 3) % NHEAD;
        int b = blk / (NHEAD * NFRAME);
        int lane = threadIdx.x & 63, wid = threadIdx.x >> 6;
        int l16 = lane & 15, quad = lane >> 4;
        const size_t hmrow = (size_t)(b * NHEAD + h) * NTOK;   // row base in hm bufs
        short* Ks = u.fa.K;
        short* VT = u.fa.VT;
        short* Pw = u.fa.P[wid];
        int tid = threadIdx.x;

        // ---- K staging: fully async, linear LDS dest, source pre-XOR-swizzled.
        const short* kbase = k_hm + hmrow * DHEAD;
        #pragma unroll
        for (int p = 0; p < 6; ++p) {
            int c = p * 256 + tid;            // rows 0..191
            int row = c >> 3, dc = c & 7;
            int tok = (row == 0) ? 0 : f * NPF + row;
            gld_lds16(kbase + (size_t)tok * DHEAD + ((dc ^ (row & 7)) * 8), &Ks[c * 8]);
        }
        if (tid < 128) {                      // rows 192..207 (pad rows -> tok 0, masked)
            int c = 1536 + tid;
            int row = c >> 3, dc = c & 7;
            int tok = (row <= 196) ? f * NPF + row : 0;
            gld_lds16(kbase + (size_t)tok * DHEAD + ((dc ^ (row & 7)) * 8), &Ks[c * 8]);
        }

        // ---- V staging: dense coalesced loads, swizzled transpose writes
        const short* vbase = v_hm + hmrow * DHEAD;
        for (int c = tid; c < NKP * 8; c += 256) {
            int j = c >> 3, dc = c & 7;
            short8 v = (short8){0, 0, 0, 0, 0, 0, 0, 0};
            if (j < NKEY) {
                int tok = (j == 0) ? 0 : f * NPF + j;
                v = *(const short8*)(vbase + (size_t)tok * DHEAD + dc * 8);
            }
            #pragma unroll
            for (int t = 0; t < 8; ++t) {
                int row = dc * 8 + t;
                int wb = row * (VST * 2) + j * 2;
                wb ^= (dc & 7) << 4;
                *(short*)((char*)VT + wb) = v[t];
            }
        }
        __syncthreads();   // drains vmcnt (gld_lds) + lgkm; the only barrier

        const float scale = 0.125f;
        const short* qbase = q_hm + hmrow * DHEAD;

        for (int qt = wid; qt < 13; qt += 4) {
            floatx4 S[13];
            for (int nt = 0; nt < 13; ++nt) S[nt] = (floatx4){0.f, 0.f, 0.f, 0.f};

            int qm = qt * 16 + l16;
            if (qm > 195) qm = 195;
            int qtok = 1 + f * NPF + qm;
            const short* qrow = qbase + (size_t)qtok * DHEAD;
            short8 afrag[2];
            afrag[0] = *(const short8*)(qrow + quad * 8);
            afrag[1] = *(const short8*)(qrow + 32 + quad * 8);

            int sw = (l16 & 7) << 4;
            for (int nt = 0; nt < 13; ++nt) {
                int kb = (nt * 16 + l16) * 128 + quad * 16;
                short8 b0 = *(const short8*)((const char*)Ks + (kb ^ sw));
                short8 b1 = *(const short8*)((const char*)Ks + ((kb + 64) ^ sw));
                S[nt] = MFMA16(afrag[0], b0, S[nt]);
                S[nt] = MFMA16(afrag[1], b1, S[nt]);
            }

            for (int nt = 0; nt < 13; ++nt) {
                int key = nt * 16 + l16;
                float mask = (key < NKEY) ? 0.f : -1e30f;
                for (int r = 0; r < 4; ++r) S[nt][r] = S[nt][r] * scale + mask;
            }

            float inv_sum[4];
            for (int r = 0; r < 4; ++r) {
                float m = -1e30f;
                for (int nt = 0; nt < 13; ++nt) m = fmaxf(m, S[nt][r]);
                for (int off = 1; off < 16; off <<= 1) m = fmaxf(m, __shfl_xor(m, off, 64));
                float s = 0.f;
                for (int nt = 0; nt < 13; ++nt) {
                    float e = __expf(S[nt][r] - m);
                    S[nt][r] = e;
                    s += e;
                }
                for (int off = 1; off < 16; off <<= 1) s += __shfl_xor(s, off, 64);
                inv_sum[r] = 1.0f / s;
            }

            floatx4 O[4];
            for (int dt = 0; dt < 4; ++dt) O[dt] = (floatx4){0.f, 0.f, 0.f, 0.f};

            #pragma unroll
            for (int nt2 = 0; nt2 < 2; ++nt2)
                #pragma unroll
                for (int r = 0; r < 4; ++r)
                    Pw[(quad * 4 + r) * PSL + nt2 * 16 + l16] = f2bf(S[nt2][r]);

            for (int ks = 0; ks < 7; ++ks) {
                const short* cur = Pw + (ks & 1) * SLICE_ELS;
                short8 af = *(const short8*)&cur[l16 * PSL + quad * 8];
                short8 bfr_[4];
                #pragma unroll
                for (int dt = 0; dt < 4; ++dt) {
                    int vrow = dt * 16 + l16;
                    int vb = vrow * (VST * 2) + ks * 64 + quad * 16;
                    vb ^= ((vrow >> 3) & 7) << 4;
                    bfr_[dt] = *(const short8*)((const char*)VT + vb);
                }
                if (ks < 6) {
                    short* nxt = Pw + ((ks + 1) & 1) * SLICE_ELS;
                    #pragma unroll
                    for (int nt2 = 0; nt2 < 2; ++nt2)
                        #pragma unroll
                        for (int r = 0; r < 4; ++r) {
                            int idx = 2 * (ks + 1) + nt2;
                            nxt[(quad * 4 + r) * PSL + nt2 * 16 + l16] =
                                (idx < 13) ? f2bf(S[idx][r]) : (short)0;
                        }
                }
                #pragma unroll
                for (int dt = 0; dt < 4; ++dt)
                    O[dt] = MFMA16(af, bfr_[dt], O[dt]);
            }

            // ---- O: LDS bounce -> coalesced stores into dense obuf
            short* Ob = Pw;
            #pragma unroll
            for (int dt = 0; dt < 4; ++dt)
                #pragma unroll
                for (int r = 0; r < 4; ++r)
                    Ob[(quad * 4 + r) * 80 + dt * 16 + l16] = f2bf(O[dt][r] * inv_sum[r]);
            int orow = lane >> 2, oseg = lane & 3;
            short8 o0 = *(const short8*)&Ob[orow * 80 + oseg * 16];
            short8 o1 = *(const short8*)&Ob[orow * 80 + oseg * 16 + 8];
            int m = qt * 16 + orow;
            if (m < NPF) {
                int tok = 1 + f * NPF + m;
                short* dst = obuf + ((size_t)b * NTOK + tok) * DIM + h * DHEAD + oseg * 16;
                *(short8*)dst = o0;
                *(short8*)(dst + 8) = o1;
            }
        }
    } else {
        // ---------------- CLS attention ----------------
        int cblk = blockIdx.x;
        int h = cblk % NHEAD, b = cblk / NHEAD;
        const size_t hmrow = (size_t)(b * NHEAD + h) * NTOK;
        int tid = threadIdx.x;
        ClsLds& ca = u.ca;

        if (tid < DHEAD) ca.qs[tid] = bf2f(q_hm[hmrow * DHEAD + tid]) * 0.125f;
        __syncthreads();

        const short* kb = k_hm + hmrow * DHEAD;
        float lmax = -1e30f;
        for (int j = tid; j < NTOK; j += 256) {
            const short* krow = kb + (size_t)j * DHEAD;
            float s = 0.f;
            #pragma unroll
            for (int c = 0; c < 8; ++c) {
                short8 kv = *(const short8*)(krow + c * 8);
                const float4* qp = (const float4*)&ca.qs[c * 8];
                float4 q0 = qp[0], q1 = qp[1];
                s += q0.x * bf2f(kv[0]); s += q0.y * bf2f(kv[1]);
                s += q0.z * bf2f(kv[2]); s += q0.w * bf2f(kv[3]);
                s += q1.x * bf2f(kv[4]); s += q1.y * bf2f(kv[5]);
                s += q1.z * bf2f(kv[6]); s += q1.w * bf2f(kv[7]);
            }
            ca.sexp[j] = s;
            lmax = fmaxf(lmax, s);
        }
        for (int off = 1; off < 64; off <<= 1) lmax = fmaxf(lmax, __shfl_xor(lmax, off, 64));
        if ((tid & 63) == 0) ca.red[tid >> 6] = lmax;
        __syncthreads();
        float mx = fmaxf(fmaxf(ca.red[0], ca.red[1]), fmaxf(ca.red[2], ca.red[3]));

        float lsum = 0.f;
        for (int j = tid; j < NTOK; j += 256) {
            float e = __expf(ca.sexp[j] - mx);
            ca.sexp[j] = e;
            lsum += e;
        }
        for (int off = 1; off < 64; off <<= 1) lsum += __shfl_xor(lsum, off, 64);
        if ((tid & 63) == 0) ca.red[4 + (tid >> 6)] = lsum;
        __syncthreads();
        float sum = ca.red[4] + ca.red[5] + ca.red[6] + ca.red[7];

        const short* vb = v_hm + hmrow * DHEAD;
        int dd = tid & 63, strip = tid >> 6;
        float acc = 0.f;
        for (int j = strip; j < NTOK; j += 4)
            acc += ca.sexp[j] * bf2f(vb[(size_t)j * DHEAD + dd]);
        ca.partial[strip][dd] = acc;
        __syncthreads();

        if (tid < DHEAD) {
            float o = (ca.partial[0][tid] + ca.partial[1][tid] +
                       ca.partial[2][tid] + ca.partial[3][tid]) / sum;
            obuf[(size_t)b * NTOK * DIM + h * DHEAD + tid] = f2bf(o);
        }
    }
}

// ---------------------------------------------------------------------------
extern "C" void kernel_launch(void* const* d_in, const int* in_sizes, int n_in,
                              void* d_out, int out_size, void* d_ws, size_t ws_size,
                              hipStream_t stream) {
    const float* x      = (const float*)d_in[0];
    const float* w_qkv  = (const float*)d_in[1];
    const float* w_proj = (const float*)d_in[2];
    const float* b_proj = (const float*)d_in[3];
    float* out = (float*)d_out;

    // ws layout: [xbf (reused as obuf) | q_hm | wqkvT | wprojT]  (~81.8 MB)
    const size_t WQKVT_EL  = (size_t)D3 * DIM;
    const size_t WPROJT_EL = (size_t)DIM * DIM;
    const size_t WS_NEEDED = (2 * HM_EL + WQKVT_EL + WPROJT_EL) * sizeof(short);

    if (ws_size < WS_NEEDED) {
        zero_out_k<<<(out_size + 255) / 256, 256, 0, stream>>>(out, out_size);
        return;
    }

    short* xbf    = (short*)d_ws;            // MROWS*DIM == HM_EL elements
    short* obuf   = xbf;                     // reuses xbf (dead after QKV GEMM)
    short* q_hm   = xbf + HM_EL;
    short* wqkvT  = q_hm + HM_EL;
    short* wprojT = wqkvT + WQKVT_EL;

    // d_out pre-proj: [k_hm | v_hm] (2*HM_EL shorts == out_size bytes exactly)
    short* k_hm = (short*)d_out;
    short* v_hm = k_hm + HM_EL;

    prep_k<<<CVT_BLKS + TRA_BLKS + TRB_BLKS, 256, 0, stream>>>(
        x, xbf, w_qkv, wqkvT, w_proj, wprojT);

    // qkv = xbf @ w_qkv -> head-major q/k/v
    {
        int gx = D3 / 256;                       // 9
        int gy = (MROWS + 255) / 256;            // 99
        int nwg = gx * gy;
        gemm256_qkv<<<nwg, 512, 0, stream>>>(
            xbf, DIM, wqkvT, q_hm, k_hm, v_hm, MROWS, DIM, gx, nwg);
    }

    attn_k<<<NFBLK + CLSBLK, 256, 0, stream>>>(q_hm, k_hm, v_hm, obuf);

    // out = obuf @ w_proj + b_proj
    {
        int gx = DIM / 128;                      // 6
        int gy = (MROWS + 127) / 128;            // 197
        int nwg = gx * gy;
        gemm_proj<<<nwg, 256, 0, stream>>>(
            obuf, DIM, wprojT, b_proj, out, DIM, MROWS, DIM, gx, nwg);
    }
}

// Round 8
// 409.078 us; speedup vs baseline: 1.2017x; 1.0576x over previous
//
#include <hip/hip_runtime.h>
#include <hip/hip_bf16.h>

// Problem constants (B=16, F=8, NP=196, D=768, H=12)
#define BATCH 16
#define NFRAME 8
#define NPF 196          // tokens per frame
#define DIM 768
#define NHEAD 12
#define DHEAD 64
#define NTOK 1569        // 1 + 8*196
#define MROWS (BATCH * NTOK)   // 25104
#define D3 (3 * DIM)           // 2304
#define NKEY 197         // CLS + frame keys
#define NKP 224          // padded keys for PV (7*32)
#define NKQ 208          // padded keys for QK (13*16)
#define VST 232          // VT LDS row stride in shorts (464 B, 16B-aligned)
#define PSL 40           // P slice row stride in shorts (80 B, 16B-aligned)
#define SLICE_ELS (16 * PSL)   // one 16q x 32key slice (640 shorts = 1280 B)
#define NFBLK (BATCH * NHEAD * NFRAME)   // 1536 frame-attn blocks
#define CLSBLK (BATCH * NHEAD)           // 192 CLS blocks (dispatched FIRST)
// head-major buffer: rows (b*NHEAD+h)*NTOK+tok, 64 shorts each
#define HM_EL ((size_t)BATCH * NHEAD * NTOK * DHEAD)   // 19,279,872 == MROWS*DIM

// merged prep kernel block ranges
#define CVT_BLKS (MROWS * DIM / 8 / 256)       // 9414 (exact)
#define TRA_GX (D3 / 32)                       // 72
#define TRA_BLKS (TRA_GX * (DIM / 32))         // 1728
#define TRB_GX (DIM / 32)                      // 24
#define TRB_BLKS (TRB_GX * (DIM / 32))         // 576

typedef __attribute__((ext_vector_type(8))) short short8;
typedef __attribute__((ext_vector_type(4))) float floatx4;

#define MFMA16(A, B, C) __builtin_amdgcn_mfma_f32_16x16x32_bf16((A), (B), (C), 0, 0, 0)

__device__ __forceinline__ float bf2f(short s) {
    union { unsigned u; float f; } x;
    x.u = ((unsigned)(unsigned short)s) << 16;
    return x.f;
}
__device__ __forceinline__ short f2bf(float f) {
    union { float f; unsigned u; } x;
    x.f = f;
    unsigned r = x.u + 0x7fffu + ((x.u >> 16) & 1u);  // RNE
    return (short)(r >> 16);
}

// async global(bf16)->LDS, 16 bytes per lane
__device__ __forceinline__ void gld_lds16(const short* g, short* l) {
    __builtin_amdgcn_global_load_lds(
        (const __attribute__((address_space(1))) void*)g,
        (__attribute__((address_space(3))) void*)l, 16, 0, 0);
}

// bijective XCD swizzle (m204)
__device__ __forceinline__ int xcd_swizzle(int d, int nwg) {
    int q = nwg >> 3, r = nwg & 7;
    int xcd = d & 7, j = d >> 3;
    return (xcd < r ? xcd * (q + 1) : r * (q + 1) + (xcd - r) * q) + j;
}

// ---------------------------------------------------------------------------
__global__ __launch_bounds__(256) void zero_out_k(float* __restrict__ out, int n) {
    int i = blockIdx.x * 256 + threadIdx.x;
    if (i < n) out[i] = 0.f;
}

// ---------------------------------------------------------------------------
// Merged prep: fp32->bf16 convert of x, plus both weight transposes.
// ---------------------------------------------------------------------------
__device__ __forceinline__ void transpose_tile(const float* __restrict__ in,
                                               short* __restrict__ out,
                                               int R, int C, int bx, int by,
                                               float (*tile)[33]) {
    int tx = threadIdx.x & 31, ty = threadIdx.x >> 5;
    int r0 = by * 32, c0 = bx * 32;
    for (int i = 0; i < 4; ++i) {
        int r = ty + i * 8;
        tile[r][tx] = in[(size_t)(r0 + r) * C + c0 + tx];
    }
    __syncthreads();
    for (int i = 0; i < 4; ++i) {
        int c = ty + i * 8;
        out[(size_t)(c0 + c) * R + r0 + tx] = f2bf(tile[tx][c]);
    }
}

__global__ __launch_bounds__(256) void prep_k(const float* __restrict__ x,
                                              short* __restrict__ xbf,
                                              const float* __restrict__ w_qkv,
                                              short* __restrict__ wqkvT,
                                              const float* __restrict__ w_proj,
                                              short* __restrict__ wprojT) {
    __shared__ float tile[32][33];
    int bid = blockIdx.x;
    if (bid < CVT_BLKS) {
        int i = bid * 256 + threadIdx.x;
        const float4* p = (const float4*)(x + (size_t)i * 8);
        float4 u0 = p[0], u1 = p[1];
        short8 t;
        t[0] = f2bf(u0.x); t[1] = f2bf(u0.y); t[2] = f2bf(u0.z); t[3] = f2bf(u0.w);
        t[4] = f2bf(u1.x); t[5] = f2bf(u1.y); t[6] = f2bf(u1.z); t[7] = f2bf(u1.w);
        *(short8*)(xbf + (size_t)i * 8) = t;
    } else if (bid < CVT_BLKS + TRA_BLKS) {
        int id = bid - CVT_BLKS;
        transpose_tile(w_qkv, wqkvT, DIM, D3, id % TRA_GX, id / TRA_GX, tile);
    } else {
        int id = bid - CVT_BLKS - TRA_BLKS;
        transpose_tile(w_proj, wprojT, DIM, DIM, id % TRB_GX, id / TRB_GX, tile);
    }
}

// ---------------------------------------------------------------------------
// proj GEMM: 128x128 tile, 4 waves (2x2), 2-slot LDS ring (32 KB => 4
// blocks/CU), counted-vmcnt pipeline: stage t+2 early, vmcnt(4) steady state
// (never 0), lgkm drained before the mid-tile barrier so the stage into the
// just-read slot is safe. Inter-block overlap (4/CU) hides per-tile stalls.
// C = A[M x K] * BT[N x K]^T + bias, fp32 out. 1-D grid + XCD swizzle.
// ---------------------------------------------------------------------------
__global__ __launch_bounds__(256, 4) void gemm_proj(const short* __restrict__ A, int lda,
                                                    const short* __restrict__ BT,
                                                    const float* __restrict__ bias,
                                                    float* __restrict__ C, int ldc,
                                                    int M, int K, int gx, int nwg) {
    __shared__ __align__(16) short lds[2][2][128 * 32];   // 32 KB

    const int tid = threadIdx.x;
    const int lane = tid & 63, w = tid >> 6;
    const int l16 = lane & 15, quad = lane >> 4;
    const int wr = w >> 1, wc = w & 1;        // wave grid 2M x 2N, 64x64 each
    const int wg = xcd_swizzle(blockIdx.x, nwg);
    const int n0 = (wg % gx) * 128, m0 = (wg / gx) * 128;
    const int T = K >> 5;

    // staging source pre-swizzle (matches read-side XOR)
    const int lcs = ((tid & 3) ^ ((tid >> 3) & 3)) * 8;
    const int srow = tid >> 2;                // rows 0..63 (j=0), +64 (j=1)

    int offA[4], offB[4];
    #pragma unroll
    for (int mt = 0; mt < 4; ++mt) {
        int row = wr * 64 + mt * 16 + l16;
        offA[mt] = row * 32 + (quad ^ ((row >> 1) & 3)) * 8;
    }
    #pragma unroll
    for (int nt = 0; nt < 4; ++nt) {
        int row = wc * 64 + nt * 16 + l16;
        offB[nt] = row * 32 + (quad ^ ((row >> 1) & 3)) * 8;
    }

    floatx4 acc[4][4];
    #pragma unroll
    for (int mt = 0; mt < 4; ++mt)
        #pragma unroll
        for (int nt = 0; nt < 4; ++nt)
            acc[mt][nt] = (floatx4){0.f, 0.f, 0.f, 0.f};

    // prologue: stage tiles 0,1
    #pragma unroll
    for (int u = 0; u < 2; ++u) {
        #pragma unroll
        for (int j = 0; j < 2; ++j) {
            int row = srow + j * 64;
            int gr = m0 + row; if (gr >= M) gr = M - 1;
            gld_lds16(A + (size_t)gr * lda + u * 32 + lcs,
                      &lds[u][0][(j * 256 + tid) * 8]);
        }
        #pragma unroll
        for (int j = 0; j < 2; ++j) {
            int row = srow + j * 64;
            gld_lds16(BT + (size_t)(n0 + row) * K + u * 32 + lcs,
                      &lds[u][1][(j * 256 + tid) * 8]);
        }
    }
    asm volatile("s_waitcnt vmcnt(4)" ::: "memory");   // tile 0 landed
    __builtin_amdgcn_s_barrier();

    for (int t = 0; t < T; ++t) {
        const int slot = t & 1;
        const short* baseA = &lds[slot][0][0];
        const short* baseB = &lds[slot][1][0];

        short8 afr[4], bfr[4];
        #pragma unroll
        for (int nt = 0; nt < 4; ++nt) bfr[nt] = *(const short8*)(baseB + offB[nt]);
        #pragma unroll
        for (int mt = 0; mt < 4; ++mt) afr[mt] = *(const short8*)(baseA + offA[mt]);

        // drain reads, then barrier: slot is now safe to overwrite
        asm volatile("s_waitcnt lgkmcnt(0)" ::: "memory");
        __builtin_amdgcn_s_barrier();

        if (t + 2 < T) {       // stage tile t+2 into the just-freed slot
            const int kst = (t + 2) << 5;
            #pragma unroll
            for (int j = 0; j < 2; ++j) {
                int row = srow + j * 64;
                int gr = m0 + row; if (gr >= M) gr = M - 1;
                gld_lds16(A + (size_t)gr * lda + kst + lcs,
                          &lds[slot][0][(j * 256 + tid) * 8]);
            }
            #pragma unroll
            for (int j = 0; j < 2; ++j) {
                int row = srow + j * 64;
                gld_lds16(BT + (size_t)(n0 + row) * K + kst + lcs,
                          &lds[slot][1][(j * 256 + tid) * 8]);
            }
        }

        __builtin_amdgcn_s_setprio(1);
        #pragma unroll
        for (int mt = 0; mt < 4; ++mt)
            #pragma unroll
            for (int nt = 0; nt < 4; ++nt)
                acc[mt][nt] = MFMA16(afr[mt], bfr[nt], acc[mt][nt]);
        __builtin_amdgcn_s_setprio(0);

        // counted: confirm tile t+1 landed; t+2 stays in flight (never 0 steady)
        if (t + 2 < T)      asm volatile("s_waitcnt vmcnt(4)" ::: "memory");
        else if (t + 1 < T) asm volatile("s_waitcnt vmcnt(0)" ::: "memory");
        __builtin_amdgcn_s_barrier();
    }

    #pragma unroll
    for (int mt = 0; mt < 4; ++mt)
        #pragma unroll
        for (int nt = 0; nt < 4; ++nt) {
            int col0 = n0 + wc * 64 + nt * 16;
            float bv = bias ? bias[col0 + l16] : 0.f;
            #pragma unroll
            for (int r = 0; r < 4; ++r) {
                int row = m0 + wr * 64 + mt * 16 + quad * 4 + r;
                if (row < M)
                    C[(size_t)row * ldc + col0 + l16] = acc[mt][nt][r] + bv;
            }
        }
}

// ---------------------------------------------------------------------------
// 256x256 QKV GEMM, BK=32, 8 waves, 4-slot LDS ring, counted-vmcnt pipeline
// (r7 loop unchanged — three schedule variants measured identical; the loop
// is shape-bound, not schedule-bound). NEW: LDS-bounced epilogue — each
// wave's (part,h) is uniform (64-aligned cols), so acc -> LDS [16][72] ->
// 2x16B coalesced head-major stores per lane per mt. Stores 128->16/thread.
// ---------------------------------------------------------------------------
__global__ __launch_bounds__(512, 2) void gemm256_qkv(const short* __restrict__ A, int lda,
                                                      const short* __restrict__ BT,
                                                      short* __restrict__ qh,
                                                      short* __restrict__ kh,
                                                      short* __restrict__ vh,
                                                      int M, int K, int gx, int nwg) {
    __shared__ __align__(16) short lds[4][2][256 * 32];

    const int tid = threadIdx.x;
    const int lane = tid & 63, w = tid >> 6;
    const int l16 = lane & 15, quad = lane >> 4;
    const int wr = w >> 2, wc = w & 3;
    const int wg = xcd_swizzle(blockIdx.x, nwg);
    const int n0 = (wg % gx) * 256, m0 = (wg / gx) * 256;
    const int T = K >> 5;

    const int lcs = ((lane & 3) ^ ((lane >> 3) & 3)) * 8;

    int offA[8], offB[4];
    #pragma unroll
    for (int mt = 0; mt < 8; ++mt) {
        int row = wr * 128 + mt * 16 + l16;
        offA[mt] = row * 32 + (quad ^ ((row >> 1) & 3)) * 8;
    }
    #pragma unroll
    for (int nt = 0; nt < 4; ++nt) {
        int row = wc * 64 + nt * 16 + l16;
        offB[nt] = row * 32 + (quad ^ ((row >> 1) & 3)) * 8;
    }

    floatx4 acc[8][4];
    #pragma unroll
    for (int mt = 0; mt < 8; ++mt)
        #pragma unroll
        for (int nt = 0; nt < 4; ++nt)
            acc[mt][nt] = (floatx4){0.f, 0.f, 0.f, 0.f};

    // ---- prologue: stage K-tiles 0,1,2 into slots 0,1,2
    for (int u = 0; u < 3; ++u) {
        const int ss = u, kst = u * 32;
        #pragma unroll
        for (int j = 0; j < 2; ++j) {
            int row = (w << 5) + (j << 4) + (lane >> 2);
            int gr = m0 + row; if (gr >= M) gr = M - 1;
            gld_lds16(A + (size_t)gr * lda + kst + lcs,
                      &lds[ss][0][((w << 7) + (j << 6) + lane) * 8]);
        }
        #pragma unroll
        for (int j = 0; j < 2; ++j) {
            int row = (w << 5) + (j << 4) + (lane >> 2);
            gld_lds16(BT + (size_t)(n0 + row) * K + kst + lcs,
                      &lds[ss][1][((w << 7) + (j << 6) + lane) * 8]);
        }
    }
    asm volatile("s_waitcnt vmcnt(8)" ::: "memory");   // tile 0 landed
    __builtin_amdgcn_s_barrier();

    for (int t = 0; t < T; ++t) {
        const int slot = t & 3;
        const int ss = (t + 3) & 3;
        const int kst = (t + 3) << 5;
        const bool do_stage = (t + 3) < T;
        const short* baseA = &lds[slot][0][0];
        const short* baseB = &lds[slot][1][0];

        if (do_stage) {
            #pragma unroll
            for (int j = 0; j < 2; ++j) {
                int row = (w << 5) + (j << 4) + (lane >> 2);
                int gr = m0 + row; if (gr >= M) gr = M - 1;
                gld_lds16(A + (size_t)gr * lda + kst + lcs,
                          &lds[ss][0][((w << 7) + (j << 6) + lane) * 8]);
            }
            #pragma unroll
            for (int j = 0; j < 2; ++j) {
                int row = (w << 5) + (j << 4) + (lane >> 2);
                gld_lds16(BT + (size_t)(n0 + row) * K + kst + lcs,
                          &lds[ss][1][((w << 7) + (j << 6) + lane) * 8]);
            }
        }

        short8 bfr[4], afr0[4], afr1[4];
        #pragma unroll
        for (int nt = 0; nt < 4; ++nt) bfr[nt] = *(const short8*)(baseB + offB[nt]);
        #pragma unroll
        for (int mt = 0; mt < 4; ++mt) afr0[mt] = *(const short8*)(baseA + offA[mt]);
        #pragma unroll
        for (int mt = 0; mt < 4; ++mt) afr1[mt] = *(const short8*)(baseA + offA[4 + mt]);

        __builtin_amdgcn_s_setprio(1);
        #pragma unroll
        for (int mt = 0; mt < 4; ++mt)
            #pragma unroll
            for (int nt = 0; nt < 4; ++nt)
                acc[mt][nt] = MFMA16(afr0[mt], bfr[nt], acc[mt][nt]);
        #pragma unroll
        for (int mt = 0; mt < 4; ++mt)
            #pragma unroll
            for (int nt = 0; nt < 4; ++nt)
                acc[4 + mt][nt] = MFMA16(afr1[mt], bfr[nt], acc[4 + mt][nt]);
        __builtin_amdgcn_s_setprio(0);

        if (t + 1 < T) {
            if (t + 3 < T)      asm volatile("s_waitcnt vmcnt(8)" ::: "memory");
            else if (t + 2 < T) asm volatile("s_waitcnt vmcnt(4)" ::: "memory");
            else                asm volatile("s_waitcnt vmcnt(0)" ::: "memory");
        }
        __builtin_amdgcn_s_barrier();        // the only barrier per K-tile
    }

    // ---- epilogue: per-wave LDS bounce -> coalesced head-major stores.
    // Wave columns n0+wc*64..+63 are one 64-aligned block => (part,h) uniform.
    short* ob = (short*)lds + w * (16 * 72);   // 2304 B/wave, lds is free now
    const int col0w = n0 + wc * 64;
    const int part = col0w / DIM;              // 0=Q 1=K 2=V
    const int within = col0w - part * DIM;
    const int h = within >> 6;
    short* base = (part == 0) ? qh : (part == 1) ? kh : vh;
    const int r0 = lane >> 2, seg0 = lane & 3;

    #pragma unroll
    for (int mt = 0; mt < 8; ++mt) {
        #pragma unroll
        for (int nt = 0; nt < 4; ++nt)
            #pragma unroll
            for (int r = 0; r < 4; ++r)
                ob[(quad * 4 + r) * 72 + nt * 16 + l16] = f2bf(acc[mt][nt][r]);
        // intra-wave LDS write->read: compiler-inserted lgkm waits
        int row = m0 + wr * 128 + mt * 16 + r0;
        if (row < M) {
            int bb = row / NTOK, tk = row - bb * NTOK;
            short* dst = base + ((size_t)(bb * NHEAD + h) * NTOK + tk) * DHEAD + seg0 * 16;
            short8 v0 = *(const short8*)&ob[r0 * 72 + seg0 * 16];
            short8 v1 = *(const short8*)&ob[r0 * 72 + seg0 * 16 + 8];
            *(short8*)dst = v0;
            *(short8*)(dst + 8) = v1;
        }
    }
}

// ---------------------------------------------------------------------------
// Merged attention (unchanged from round 6/7).
// ---------------------------------------------------------------------------
struct FrameLds {
    short K[NKQ * DHEAD];           // 26624 B, [key][d], 16B-chunk XOR swizzle
    short VT[DHEAD * VST];          // 29696 B, [d][key] swizzled
    short P[4][2 * SLICE_ELS];      // 10240 B, per-wave P slices / O bounce
};
struct ClsLds {
    float qs[DHEAD];
    float sexp[NTOK];
    float red[8];
    float partial[4][DHEAD];
};
union AttnLds {
    FrameLds fa;
    ClsLds ca;
};

__global__ __launch_bounds__(256, 2) void attn_k(const short* __restrict__ q_hm,
                                                 const short* __restrict__ k_hm,
                                                 const short* __restrict__ v_hm,
                                                 short* __restrict__ obuf) {
    __shared__ __align__(16) AttnLds u;

    if (blockIdx.x >= CLSBLK) {
        // ---------------- frame attention ----------------
        int blk = blockIdx.x - CLSBLK;
        int f = blk & 7;
        int h = (blk >> 3) % NHEAD;
        int b = blk / (NHEAD * NFRAME);
        int lane = threadIdx.x & 63, wid = threadIdx.x >> 6;
        int l16 = lane & 15, quad = lane >> 4;
        const size_t hmrow = (size_t)(b * NHEAD + h) * NTOK;   // row base in hm bufs
        short* Ks = u.fa.K;
        short* VT = u.fa.VT;
        short* Pw = u.fa.P[wid];
        int tid = threadIdx.x;

        // ---- K staging: fully async, linear LDS dest, source pre-XOR-swizzled.
        const short* kbase = k_hm + hmrow * DHEAD;
        #pragma unroll
        for (int p = 0; p < 6; ++p) {
            int c = p * 256 + tid;            // rows 0..191
            int row = c >> 3, dc = c & 7;
            int tok = (row == 0) ? 0 : f * NPF + row;
            gld_lds16(kbase + (size_t)tok * DHEAD + ((dc ^ (row & 7)) * 8), &Ks[c * 8]);
        }
        if (tid < 128) {                      // rows 192..207 (pad rows -> tok 0, masked)
            int c = 1536 + tid;
            int row = c >> 3, dc = c & 7;
            int tok = (row <= 196) ? f * NPF + row : 0;
            gld_lds16(kbase + (size_t)tok * DHEAD + ((dc ^ (row & 7)) * 8), &Ks[c * 8]);
        }

        // ---- V staging: dense coalesced loads, swizzled transpose writes
        const short* vbase = v_hm + hmrow * DHEAD;
        for (int c = tid; c < NKP * 8; c += 256) {
            int j = c >> 3, dc = c & 7;
            short8 v = (short8){0, 0, 0, 0, 0, 0, 0, 0};
            if (j < NKEY) {
                int tok = (j == 0) ? 0 : f * NPF + j;
                v = *(const short8*)(vbase + (size_t)tok * DHEAD + dc * 8);
            }
            #pragma unroll
            for (int t = 0; t < 8; ++t) {
                int row = dc * 8 + t;
                int wb = row * (VST * 2) + j * 2;
                wb ^= (dc & 7) << 4;
                *(short*)((char*)VT + wb) = v[t];
            }
        }
        __syncthreads();   // drains vmcnt (gld_lds) + lgkm; the only barrier

        const float scale = 0.125f;
        const short* qbase = q_hm + hmrow * DHEAD;

        for (int qt = wid; qt < 13; qt += 4) {
            floatx4 S[13];
            for (int nt = 0; nt < 13; ++nt) S[nt] = (floatx4){0.f, 0.f, 0.f, 0.f};

            int qm = qt * 16 + l16;
            if (qm > 195) qm = 195;
            int qtok = 1 + f * NPF + qm;
            const short* qrow = qbase + (size_t)qtok * DHEAD;
            short8 afrag[2];
            afrag[0] = *(const short8*)(qrow + quad * 8);
            afrag[1] = *(const short8*)(qrow + 32 + quad * 8);

            int sw = (l16 & 7) << 4;
            for (int nt = 0; nt < 13; ++nt) {
                int kb = (nt * 16 + l16) * 128 + quad * 16;
                short8 b0 = *(const short8*)((const char*)Ks + (kb ^ sw));
                short8 b1 = *(const short8*)((const char*)Ks + ((kb + 64) ^ sw));
                S[nt] = MFMA16(afrag[0], b0, S[nt]);
                S[nt] = MFMA16(afrag[1], b1, S[nt]);
            }

            for (int nt = 0; nt < 13; ++nt) {
                int key = nt * 16 + l16;
                float mask = (key < NKEY) ? 0.f : -1e30f;
                for (int r = 0; r < 4; ++r) S[nt][r] = S[nt][r] * scale + mask;
            }

            float inv_sum[4];
            for (int r = 0; r < 4; ++r) {
                float m = -1e30f;
                for (int nt = 0; nt < 13; ++nt) m = fmaxf(m, S[nt][r]);
                for (int off = 1; off < 16; off <<= 1) m = fmaxf(m, __shfl_xor(m, off, 64));
                float s = 0.f;
                for (int nt = 0; nt < 13; ++nt) {
                    float e = __expf(S[nt][r] - m);
                    S[nt][r] = e;
                    s += e;
                }
                for (int off = 1; off < 16; off <<= 1) s += __shfl_xor(s, off, 64);
                inv_sum[r] = 1.0f / s;
            }

            floatx4 O[4];
            for (int dt = 0; dt < 4; ++dt) O[dt] = (floatx4){0.f, 0.f, 0.f, 0.f};

            #pragma unroll
            for (int nt2 = 0; nt2 < 2; ++nt2)
                #pragma unroll
                for (int r = 0; r < 4; ++r)
                    Pw[(quad * 4 + r) * PSL + nt2 * 16 + l16] = f2bf(S[nt2][r]);

            for (int ks = 0; ks < 7; ++ks) {
                const short* cur = Pw + (ks & 1) * SLICE_ELS;
                short8 af = *(const short8*)&cur[l16 * PSL + quad * 8];
                short8 bfr_[4];
                #pragma unroll
                for (int dt = 0; dt < 4; ++dt) {
                    int vrow = dt * 16 + l16;
                    int vb = vrow * (VST * 2) + ks * 64 + quad * 16;
                    vb ^= ((vrow >> 3) & 7) << 4;
                    bfr_[dt] = *(const short8*)((const char*)VT + vb);
                }
                if (ks < 6) {
                    short* nxt = Pw + ((ks + 1) & 1) * SLICE_ELS;
                    #pragma unroll
                    for (int nt2 = 0; nt2 < 2; ++nt2)
                        #pragma unroll
                        for (int r = 0; r < 4; ++r) {
                            int idx = 2 * (ks + 1) + nt2;
                            nxt[(quad * 4 + r) * PSL + nt2 * 16 + l16] =
                                (idx < 13) ? f2bf(S[idx][r]) : (short)0;
                        }
                }
                #pragma unroll
                for (int dt = 0; dt < 4; ++dt)
                    O[dt] = MFMA16(af, bfr_[dt], O[dt]);
            }

            // ---- O: LDS bounce -> coalesced stores into dense obuf
            short* Ob = Pw;
            #pragma unroll
            for (int dt = 0; dt < 4; ++dt)
                #pragma unroll
                for (int r = 0; r < 4; ++r)
                    Ob[(quad * 4 + r) * 80 + dt * 16 + l16] = f2bf(O[dt][r] * inv_sum[r]);
            int orow = lane >> 2, oseg = lane & 3;
            short8 o0 = *(const short8*)&Ob[orow * 80 + oseg * 16];
            short8 o1 = *(const short8*)&Ob[orow * 80 + oseg * 16 + 8];
            int m = qt * 16 + orow;
            if (m < NPF) {
                int tok = 1 + f * NPF + m;
                short* dst = obuf + ((size_t)b * NTOK + tok) * DIM + h * DHEAD + oseg * 16;
                *(short8*)dst = o0;
                *(short8*)(dst + 8) = o1;
            }
        }
    } else {
        // ---------------- CLS attention ----------------
        int cblk = blockIdx.x;
        int h = cblk % NHEAD, b = cblk / NHEAD;
        const size_t hmrow = (size_t)(b * NHEAD + h) * NTOK;
        int tid = threadIdx.x;
        ClsLds& ca = u.ca;

        if (tid < DHEAD) ca.qs[tid] = bf2f(q_hm[hmrow * DHEAD + tid]) * 0.125f;
        __syncthreads();

        const short* kb = k_hm + hmrow * DHEAD;
        float lmax = -1e30f;
        for (int j = tid; j < NTOK; j += 256) {
            const short* krow = kb + (size_t)j * DHEAD;
            float s = 0.f;
            #pragma unroll
            for (int c = 0; c < 8; ++c) {
                short8 kv = *(const short8*)(krow + c * 8);
                const float4* qp = (const float4*)&ca.qs[c * 8];
                float4 q0 = qp[0], q1 = qp[1];
                s += q0.x * bf2f(kv[0]); s += q0.y * bf2f(kv[1]);
                s += q0.z * bf2f(kv[2]); s += q0.w * bf2f(kv[3]);
                s += q1.x * bf2f(kv[4]); s += q1.y * bf2f(kv[5]);
                s += q1.z * bf2f(kv[6]); s += q1.w * bf2f(kv[7]);
            }
            ca.sexp[j] = s;
            lmax = fmaxf(lmax, s);
        }
        for (int off = 1; off < 64; off <<= 1) lmax = fmaxf(lmax, __shfl_xor(lmax, off, 64));
        if ((tid & 63) == 0) ca.red[tid >> 6] = lmax;
        __syncthreads();
        float mx = fmaxf(fmaxf(ca.red[0], ca.red[1]), fmaxf(ca.red[2], ca.red[3]));

        float lsum = 0.f;
        for (int j = tid; j < NTOK; j += 256) {
            float e = __expf(ca.sexp[j] - mx);
            ca.sexp[j] = e;
            lsum += e;
        }
        for (int off = 1; off < 64; off <<= 1) lsum += __shfl_xor(lsum, off, 64);
        if ((tid & 63) == 0) ca.red[4 + (tid >> 6)] = lsum;
        __syncthreads();
        float sum = ca.red[4] + ca.red[5] + ca.red[6] + ca.red[7];

        const short* vb = v_hm + hmrow * DHEAD;
        int dd = tid & 63, strip = tid >> 6;
        float acc = 0.f;
        for (int j = strip; j < NTOK; j += 4)
            acc += ca.sexp[j] * bf2f(vb[(size_t)j * DHEAD + dd]);
        ca.partial[strip][dd] = acc;
        __syncthreads();

        if (tid < DHEAD) {
            float o = (ca.partial[0][tid] + ca.partial[1][tid] +
                       ca.partial[2][tid] + ca.partial[3][tid]) / sum;
            obuf[(size_t)b * NTOK * DIM + h * DHEAD + tid] = f2bf(o);
        }
    }
}

// ---------------------------------------------------------------------------
extern "C" void kernel_launch(void* const* d_in, const int* in_sizes, int n_in,
                              void* d_out, int out_size, void* d_ws, size_t ws_size,
                              hipStream_t stream) {
    const float* x      = (const float*)d_in[0];
    const float* w_qkv  = (const float*)d_in[1];
    const float* w_proj = (const float*)d_in[2];
    const float* b_proj = (const float*)d_in[3];
    float* out = (float*)d_out;

    // ws layout: [xbf (reused as obuf) | q_hm | wqkvT | wprojT]  (~81.8 MB)
    const size_t WQKVT_EL  = (size_t)D3 * DIM;
    const size_t WPROJT_EL = (size_t)DIM * DIM;
    const size_t WS_NEEDED = (2 * HM_EL + WQKVT_EL + WPROJT_EL) * sizeof(short);

    if (ws_size < WS_NEEDED) {
        zero_out_k<<<(out_size + 255) / 256, 256, 0, stream>>>(out, out_size);
        return;
    }

    short* xbf    = (short*)d_ws;            // MROWS*DIM == HM_EL elements
    short* obuf   = xbf;                     // reuses xbf (dead after QKV GEMM)
    short* q_hm   = xbf + HM_EL;
    short* wqkvT  = q_hm + HM_EL;
    short* wprojT = wqkvT + WQKVT_EL;

    // d_out pre-proj: [k_hm | v_hm] (2*HM_EL shorts == out_size bytes exactly)
    short* k_hm = (short*)d_out;
    short* v_hm = k_hm + HM_EL;

    prep_k<<<CVT_BLKS + TRA_BLKS + TRB_BLKS, 256, 0, stream>>>(
        x, xbf, w_qkv, wqkvT, w_proj, wprojT);

    // qkv = xbf @ w_qkv -> head-major q/k/v
    {
        int gx = D3 / 256;                       // 9
        int gy = (MROWS + 255) / 256;            // 99
        int nwg = gx * gy;
        gemm256_qkv<<<nwg, 512, 0, stream>>>(
            xbf, DIM, wqkvT, q_hm, k_hm, v_hm, MROWS, DIM, gx, nwg);
    }

    attn_k<<<NFBLK + CLSBLK, 256, 0, stream>>>(q_hm, k_hm, v_hm, obuf);

    // out = obuf @ w_proj + b_proj
    {
        int gx = DIM / 128;                      // 6
        int gy = (MROWS + 127) / 128;            // 197
        int nwg = gx * gy;
        gemm_proj<<<nwg, 256, 0, stream>>>(
            obuf, DIM, wprojT, b_proj, out, DIM, MROWS, DIM, gx, nwg);
    }
}